// Round 1
// baseline (1450.335 us; speedup 1.0000x reference)
//
#include <hip/hip_runtime.h>

typedef __bf16 bf16x8 __attribute__((ext_vector_type(8)));
typedef float f32x4 __attribute__((ext_vector_type(4)));

#define MFMA16(a, b, c) __builtin_amdgcn_mfma_f32_16x16x32_bf16(a, b, c, 0, 0, 0)

__device__ __forceinline__ unsigned short f2bf(float x) {
  unsigned u = __float_as_uint(x);
  u += 0x7FFF + ((u >> 16) & 1);   // round-to-nearest-even
  return (unsigned short)(u >> 16);
}
__device__ __forceinline__ float bf2f(unsigned short h) {
  return __uint_as_float(((unsigned)h) << 16);
}
__device__ __forceinline__ bf16x8 ldb8(const unsigned short* p) {
  return *reinterpret_cast<const bf16x8*>(p);
}

// ---------------- fp32 -> bf16 (hi, optional lo residual) ----------------
__global__ __launch_bounds__(256) void prep_kernel(const float* __restrict__ src,
                                                   unsigned short* __restrict__ hi,
                                                   unsigned short* __restrict__ lo,
                                                   int n4) {
  int i = blockIdx.x * 256 + threadIdx.x;
  if (i >= n4) return;
  float4 x = reinterpret_cast<const float4*>(src)[i];
  unsigned short h0 = f2bf(x.x), h1 = f2bf(x.y), h2 = f2bf(x.z), h3 = f2bf(x.w);
  reinterpret_cast<ushort4*>(hi)[i] = make_ushort4(h0, h1, h2, h3);
  if (lo) {
    reinterpret_cast<ushort4*>(lo)[i] =
        make_ushort4(f2bf(x.x - bf2f(h0)), f2bf(x.y - bf2f(h1)),
                     f2bf(x.z - bf2f(h2)), f2bf(x.w - bf2f(h3)));
  }
}

// ---------------- GEMM: y[m,n] = sum_k A[m,k]*B[n,k] + bias[n] ----------------
// MODE 0: split inputs (A=Ah+Al, B=Bh+Bl), output split bf16 pair, head-split [b,h,s,d]
// MODE 1: single inputs, output bf16 transposed per head [b,h,d,s]
// MODE 2: single inputs, output fp32 row-major [m,n]
template <int MODE>
__global__ __launch_bounds__(256) void gemm_kernel(
    const unsigned short* __restrict__ Ah, const unsigned short* __restrict__ Al,
    const unsigned short* __restrict__ Bh, const unsigned short* __restrict__ Bl,
    const float* __restrict__ bias,
    unsigned short* __restrict__ out_hi, unsigned short* __restrict__ out_lo,
    float* __restrict__ out_f) {
  constexpr bool SPLIT = (MODE == 0);
  __shared__ __align__(16) unsigned short Ahs[128 * 32];
  __shared__ __align__(16) unsigned short Bhs[128 * 32];
  __shared__ __align__(16) unsigned short Als[128 * 32];
  __shared__ __align__(16) unsigned short Bls[128 * 32];

  const int tid = threadIdx.x;
  const int tm = blockIdx.x & 31, tn = blockIdx.x >> 5;
  const int m0 = tm * 128, n0 = tn * 128;
  const int w = tid >> 6, l = tid & 63, lg = l >> 4, lr = l & 15;
  const int wr = w >> 1, wc = w & 1;
  const int srow = tid >> 2, scol = (tid & 3) * 8;

  f32x4 acc[4][4] = {};

  for (int kt = 0; kt < 32; ++kt) {
    const int k0 = kt * 32;
    uint4 ra[2], rb[2], ral[2], rbl[2];
#pragma unroll
    for (int it = 0; it < 2; ++it) {
      const int row = it * 64 + srow;
      size_t ga = (size_t)(m0 + row) * 1024 + k0 + scol;
      size_t gb = (size_t)(n0 + row) * 1024 + k0 + scol;
      ra[it] = *reinterpret_cast<const uint4*>(Ah + ga);
      rb[it] = *reinterpret_cast<const uint4*>(Bh + gb);
      if (SPLIT) {
        ral[it] = *reinterpret_cast<const uint4*>(Al + ga);
        rbl[it] = *reinterpret_cast<const uint4*>(Bl + gb);
      }
    }
    __syncthreads();   // previous iteration's LDS reads complete
#pragma unroll
    for (int it = 0; it < 2; ++it) {
      const int eo = (it * 256 + tid) * 8;
      *reinterpret_cast<uint4*>(Ahs + eo) = ra[it];
      *reinterpret_cast<uint4*>(Bhs + eo) = rb[it];
      if (SPLIT) {
        *reinterpret_cast<uint4*>(Als + eo) = ral[it];
        *reinterpret_cast<uint4*>(Bls + eo) = rbl[it];
      }
    }
    __syncthreads();

    bf16x8 fa[4], fb[4], fal[4], fbl[4];
#pragma unroll
    for (int i = 0; i < 4; ++i) {
      fa[i] = ldb8(Ahs + (wr * 64 + i * 16 + lr) * 32 + lg * 8);
      fb[i] = ldb8(Bhs + (wc * 64 + i * 16 + lr) * 32 + lg * 8);
      if (SPLIT) {
        fal[i] = ldb8(Als + (wr * 64 + i * 16 + lr) * 32 + lg * 8);
        fbl[i] = ldb8(Bls + (wc * 64 + i * 16 + lr) * 32 + lg * 8);
      }
    }
#pragma unroll
    for (int i = 0; i < 4; ++i)
#pragma unroll
      for (int j = 0; j < 4; ++j) {
        acc[i][j] = MFMA16(fa[i], fb[j], acc[i][j]);
        if (SPLIT) {
          acc[i][j] = MFMA16(fa[i], fbl[j], acc[i][j]);
          acc[i][j] = MFMA16(fal[i], fb[j], acc[i][j]);
        }
      }
    __syncthreads();   // MFMA frag reads done before next iteration's writes
  }

  // epilogue: C/D layout col=lane&15, row=(lane>>4)*4+reg [m89/m91]
#pragma unroll
  for (int i = 0; i < 4; ++i) {
    const int mrow = m0 + wr * 64 + i * 16 + lg * 4;
#pragma unroll
    for (int j = 0; j < 4; ++j) {
      const int ncol = n0 + wc * 64 + j * 16 + lr;
      const float bv = bias[ncol];
#pragma unroll
      for (int r = 0; r < 4; ++r) {
        const int m = mrow + r;
        const float v = acc[i][j][r] + bv;
        if (MODE == 2) {
          out_f[(size_t)m * 1024 + ncol] = v;
        } else {
          const int bb = m >> 11, s = m & 2047, hh = ncol >> 6, d = ncol & 63;
          if (MODE == 0) {
            const size_t off = ((size_t)(bb * 16 + hh) * 2048 + s) * 64 + d;
            const unsigned short hv = f2bf(v);
            out_hi[off] = hv;
            out_lo[off] = f2bf(v - bf2f(hv));
          } else {
            out_hi[((size_t)(bb * 16 + hh) * 64 + d) * 2048 + s] = f2bf(v);
          }
        }
      }
    }
  }
}

// ---------------- fused attention: QK^T (split-bf16) + softmax + attn-write + PV ----------------
__global__ __launch_bounds__(256) void attn_kernel(
    const unsigned short* __restrict__ qh_hi, const unsigned short* __restrict__ qh_lo,
    const unsigned short* __restrict__ kh_hi, const unsigned short* __restrict__ kh_lo,
    const unsigned short* __restrict__ vT,
    const float* __restrict__ rel_bias, const float* __restrict__ mask,
    float* __restrict__ attn_out, unsigned short* __restrict__ o_bf) {
  __shared__ float rb[2112];
  __shared__ __align__(16) unsigned short p_lds[64 * 72];  // stride 72: 2-way bank alias only

  const int bh = blockIdx.x >> 5, qt = blockIdx.x & 31;
  const int b = bh >> 4, h = bh & 15;
  const int q0 = qt * 64;
  const int tid = threadIdx.x;
  const int w = tid >> 6, l = tid & 63, lg = l >> 4, lr = l & 15;

  for (int t = tid; t < 2111; t += 256) rb[t] = rel_bias[(q0 + t) * 16 + h];

  const size_t bh_off = (size_t)bh * 2048 * 64;
  const unsigned short* qhh = qh_hi + bh_off;
  const unsigned short* qhl = qh_lo + bh_off;
  const unsigned short* khh = kh_hi + bh_off;
  const unsigned short* khl = kh_lo + bh_off;
  const unsigned short* vTb = vT + bh_off;
  const float* maskb = mask + (size_t)b * 2048 * 2048;
  float* attn_bh = attn_out + (size_t)bh * 2048 * 2048;

  bf16x8 qfh[2], qfl[2];
  {
    const size_t qrow = (size_t)(q0 + w * 16 + lr) * 64;
    qfh[0] = ldb8(qhh + qrow + lg * 8);
    qfh[1] = ldb8(qhh + qrow + 32 + lg * 8);
    qfl[0] = ldb8(qhl + qrow + lg * 8);
    qfl[1] = ldb8(qhl + qrow + 32 + lg * 8);
  }
  __syncthreads();  // rb ready

  const int qbase = w * 16 + lg * 4;  // C/D row base within the 64-row tile
  float m_run[4] = {-1e30f, -1e30f, -1e30f, -1e30f};
  float s_run[4] = {0.f, 0.f, 0.f, 0.f};

  // ---- pass 1: row max + sum (online) ----
  for (int kt = 0; kt < 32; ++kt) {
    float lgt[4][4];
#pragma unroll
    for (int c = 0; c < 4; ++c) {
      const int kc = kt * 64 + c * 16 + lr;
      const size_t krow = (size_t)kc * 64;
      f32x4 acc = {};
#pragma unroll
      for (int kk = 0; kk < 2; ++kk) {
        bf16x8 kfh = ldb8(khh + krow + kk * 32 + lg * 8);
        bf16x8 kfl = ldb8(khl + krow + kk * 32 + lg * 8);
        acc = MFMA16(qfh[kk], kfh, acc);
        acc = MFMA16(qfh[kk], kfl, acc);
        acc = MFMA16(qfl[kk], kfh, acc);
      }
#pragma unroll
      for (int r = 0; r < 4; ++r) {
        const int qr = q0 + qbase + r;
        const float mv = maskb[(size_t)qr * 2048 + kc];
        lgt[c][r] = acc[r] * 0.125f + rb[qbase + r - kc + 2047] + mv * -1e9f;
      }
    }
#pragma unroll
    for (int r = 0; r < 4; ++r) {
      float mx = fmaxf(fmaxf(lgt[0][r], lgt[1][r]), fmaxf(lgt[2][r], lgt[3][r]));
      mx = fmaxf(mx, __shfl_xor(mx, 1));
      mx = fmaxf(mx, __shfl_xor(mx, 2));
      mx = fmaxf(mx, __shfl_xor(mx, 4));
      mx = fmaxf(mx, __shfl_xor(mx, 8));
      const float nm = fmaxf(m_run[r], mx);
      float ps = __expf(lgt[0][r] - nm) + __expf(lgt[1][r] - nm) +
                 __expf(lgt[2][r] - nm) + __expf(lgt[3][r] - nm);
      ps += __shfl_xor(ps, 1);
      ps += __shfl_xor(ps, 2);
      ps += __shfl_xor(ps, 4);
      ps += __shfl_xor(ps, 8);
      s_run[r] = s_run[r] * __expf(m_run[r] - nm) + ps;
      m_run[r] = nm;
    }
  }
  float inv_s[4];
#pragma unroll
  for (int r = 0; r < 4; ++r) inv_s[r] = 1.0f / s_run[r];

  // ---- pass 2: recompute logits, write attn, PV ----
  f32x4 acc_o[4] = {};
  for (int kt = 0; kt < 32; ++kt) {
#pragma unroll
    for (int c = 0; c < 4; ++c) {
      const int kc = kt * 64 + c * 16 + lr;
      const size_t krow = (size_t)kc * 64;
      f32x4 acc = {};
#pragma unroll
      for (int kk = 0; kk < 2; ++kk) {
        bf16x8 kfh = ldb8(khh + krow + kk * 32 + lg * 8);
        bf16x8 kfl = ldb8(khl + krow + kk * 32 + lg * 8);
        acc = MFMA16(qfh[kk], kfh, acc);
        acc = MFMA16(qfh[kk], kfl, acc);
        acc = MFMA16(qfl[kk], kfh, acc);
      }
#pragma unroll
      for (int r = 0; r < 4; ++r) {
        const int qr = q0 + qbase + r;
        const float mv = maskb[(size_t)qr * 2048 + kc];
        const float lgv = acc[r] * 0.125f + rb[qbase + r - kc + 2047] + mv * -1e9f;
        const float p = __expf(lgv - m_run[r]) * inv_s[r];
        attn_bh[(size_t)qr * 2048 + kc] = p;
        p_lds[(qbase + r) * 72 + c * 16 + lr] = f2bf(p);
      }
    }
    __syncthreads();
    bf16x8 pf0 = ldb8(p_lds + (w * 16 + lr) * 72 + lg * 8);
    bf16x8 pf1 = ldb8(p_lds + (w * 16 + lr) * 72 + 32 + lg * 8);
#pragma unroll
    for (int n = 0; n < 4; ++n) {
      bf16x8 vf0 = ldb8(vTb + (size_t)(n * 16 + lr) * 2048 + kt * 64 + lg * 8);
      bf16x8 vf1 = ldb8(vTb + (size_t)(n * 16 + lr) * 2048 + kt * 64 + 32 + lg * 8);
      acc_o[n] = MFMA16(pf0, vf0, acc_o[n]);
      acc_o[n] = MFMA16(pf1, vf1, acc_o[n]);
    }
    __syncthreads();
  }

  // epilogue: write per-head output in [b,s,h,d] (= dense GEMM A layout) as bf16
#pragma unroll
  for (int n = 0; n < 4; ++n)
#pragma unroll
    for (int r = 0; r < 4; ++r) {
      const int qr = q0 + qbase + r;
      const int d = n * 16 + lr;
      o_bf[((size_t)(b * 2048 + qr) * 16 + h) * 64 + d] = f2bf(acc_o[n][r]);
    }
}

// ---------------- host ----------------
extern "C" void kernel_launch(void* const* d_in, const int* in_sizes, int n_in,
                              void* d_out, int out_size, void* d_ws, size_t ws_size,
                              hipStream_t stream) {
  const float* q = (const float*)d_in[0];
  const float* k = (const float*)d_in[1];
  const float* v = (const float*)d_in[2];
  const float* mask = (const float*)d_in[3];
  const float* wq_w = (const float*)d_in[4];
  const float* wq_b = (const float*)d_in[5];
  const float* wk_w = (const float*)d_in[6];
  const float* wk_b = (const float*)d_in[7];
  const float* wv_w = (const float*)d_in[8];
  const float* wv_b = (const float*)d_in[9];
  const float* dw = (const float*)d_in[10];
  const float* db = (const float*)d_in[11];
  const float* rel = (const float*)d_in[12];

  char* ws = (char*)d_ws;
  unsigned short* q_hi = (unsigned short*)(ws + 0);
  unsigned short* q_lo = (unsigned short*)(ws + 8388608);
  unsigned short* k_hi = (unsigned short*)(ws + 16777216);
  unsigned short* k_lo = (unsigned short*)(ws + 25165824);
  unsigned short* v_bf = (unsigned short*)(ws + 33554432);
  unsigned short* wq_hi = (unsigned short*)(ws + 41943040);
  unsigned short* wq_lo = (unsigned short*)(ws + 44040192);
  unsigned short* wk_hi = (unsigned short*)(ws + 46137344);
  unsigned short* wk_lo = (unsigned short*)(ws + 48234496);
  unsigned short* wv_bf = (unsigned short*)(ws + 50331648);
  unsigned short* dw_bf = (unsigned short*)(ws + 52428800);
  unsigned short* qh_hi = (unsigned short*)(ws + 54525952);
  unsigned short* qh_lo = (unsigned short*)(ws + 62914560);
  unsigned short* kh_hi = (unsigned short*)(ws + 71303168);
  unsigned short* kh_lo = (unsigned short*)(ws + 79691776);
  unsigned short* vhT  = (unsigned short*)(ws + 88080384);
  unsigned short* o_bf = (unsigned short*)(ws + 96468992);

  float* out = (float*)d_out;
  float* attn_out = out + 4194304;

  // fp32 -> bf16 (split where the logits path needs precision)
  prep_kernel<<<4096, 256, 0, stream>>>(q, q_hi, q_lo, 1048576);
  prep_kernel<<<4096, 256, 0, stream>>>(k, k_hi, k_lo, 1048576);
  prep_kernel<<<4096, 256, 0, stream>>>(v, v_bf, nullptr, 1048576);
  prep_kernel<<<1024, 256, 0, stream>>>(wq_w, wq_hi, wq_lo, 262144);
  prep_kernel<<<1024, 256, 0, stream>>>(wk_w, wk_hi, wk_lo, 262144);
  prep_kernel<<<1024, 256, 0, stream>>>(wv_w, wv_bf, nullptr, 262144);
  prep_kernel<<<1024, 256, 0, stream>>>(dw, dw_bf, nullptr, 262144);

  // projections
  gemm_kernel<0><<<256, 256, 0, stream>>>(q_hi, q_lo, wq_hi, wq_lo, wq_b, qh_hi, qh_lo, nullptr);
  gemm_kernel<0><<<256, 256, 0, stream>>>(k_hi, k_lo, wk_hi, wk_lo, wk_b, kh_hi, kh_lo, nullptr);
  gemm_kernel<1><<<256, 256, 0, stream>>>(v_bf, nullptr, wv_bf, nullptr, wv_b, vhT, nullptr, nullptr);

  // fused attention (writes attn output + per-head context)
  attn_kernel<<<1024, 256, 0, stream>>>(qh_hi, qh_lo, kh_hi, kh_lo, vhT, rel, mask, attn_out, o_bf);

  // output dense projection
  gemm_kernel<2><<<256, 256, 0, stream>>>(o_bf, nullptr, dw_bf, nullptr, db, nullptr, nullptr, out);
}

// Round 2
// 877.564 us; speedup vs baseline: 1.6527x; 1.6527x over previous
//
#include <hip/hip_runtime.h>

typedef __bf16 bf16x8 __attribute__((ext_vector_type(8)));
typedef float f32x4 __attribute__((ext_vector_type(4)));
typedef unsigned int u32;

#define MFMA16(a, b, c) __builtin_amdgcn_mfma_f32_16x16x32_bf16(a, b, c, 0, 0, 0)

#if __has_builtin(__builtin_amdgcn_exp2f)
#define EXP2F(x) __builtin_amdgcn_exp2f(x)
#else
#define EXP2F(x) exp2f(x)
#endif

#define LOG2E 1.44269504088896340736f

__device__ __forceinline__ unsigned short f2bf(float x) {
  unsigned u = __float_as_uint(x);
  u += 0x7FFF + ((u >> 16) & 1);   // round-to-nearest-even
  return (unsigned short)(u >> 16);
}
__device__ __forceinline__ float bf2f(unsigned short h) {
  return __uint_as_float(((unsigned)h) << 16);
}
__device__ __forceinline__ bf16x8 ldb8(const unsigned short* p) {
  return *reinterpret_cast<const bf16x8*>(p);
}
__device__ __forceinline__ void gload_lds16(const void* g, void* lds) {
  __builtin_amdgcn_global_load_lds(
      (const __attribute__((address_space(1))) u32*)g,
      (__attribute__((address_space(3))) u32*)lds, 16, 0, 0);
}

// ---------------- fp32 -> bf16 (hi, optional lo residual) ----------------
__global__ __launch_bounds__(256) void prep_kernel(const float* __restrict__ src,
                                                   unsigned short* __restrict__ hi,
                                                   unsigned short* __restrict__ lo,
                                                   int n4) {
  int i = blockIdx.x * 256 + threadIdx.x;
  if (i >= n4) return;
  float4 x = reinterpret_cast<const float4*>(src)[i];
  unsigned short h0 = f2bf(x.x), h1 = f2bf(x.y), h2 = f2bf(x.z), h3 = f2bf(x.w);
  reinterpret_cast<ushort4*>(hi)[i] = make_ushort4(h0, h1, h2, h3);
  if (lo) {
    reinterpret_cast<ushort4*>(lo)[i] =
        make_ushort4(f2bf(x.x - bf2f(h0)), f2bf(x.y - bf2f(h1)),
                     f2bf(x.z - bf2f(h2)), f2bf(x.w - bf2f(h3)));
  }
}

// ---------------- mask -> bf16( mask * -1e9 * log2e ) ----------------
__global__ __launch_bounds__(256) void prep_mask_kernel(const float* __restrict__ src,
                                                        unsigned short* __restrict__ dst,
                                                        int n4) {
  int i = blockIdx.x * 256 + threadIdx.x;
  if (i >= n4) return;
  float4 x = reinterpret_cast<const float4*>(src)[i];
  const float c = -1e9f * LOG2E;
  reinterpret_cast<ushort4*>(dst)[i] =
      make_ushort4(f2bf(x.x * c), f2bf(x.y * c), f2bf(x.z * c), f2bf(x.w * c));
}

// ---------------- GEMM: y[m,n] = sum_k A[m,k]*B[n,k] + bias[n] ----------------
// MODE 0: split inputs, output split bf16 pair, head-split [b,h,s,d]
// MODE 1: single inputs, output bf16 transposed per head [b,h,d,s]
// MODE 2: single inputs, output fp32 row-major [m,n]
template <int MODE>
__global__ __launch_bounds__(256) void gemm_kernel(
    const unsigned short* __restrict__ Ah, const unsigned short* __restrict__ Al,
    const unsigned short* __restrict__ Bh, const unsigned short* __restrict__ Bl,
    const float* __restrict__ bias,
    unsigned short* __restrict__ out_hi, unsigned short* __restrict__ out_lo,
    float* __restrict__ out_f) {
  constexpr bool SPLIT = (MODE == 0);
  __shared__ __align__(16) unsigned short Ahs[128 * 32];
  __shared__ __align__(16) unsigned short Bhs[128 * 32];
  __shared__ __align__(16) unsigned short Als[128 * 32];
  __shared__ __align__(16) unsigned short Bls[128 * 32];

  const int tid = threadIdx.x;
  const int tm = blockIdx.x & 31, tn = blockIdx.x >> 5;
  const int m0 = tm * 128, n0 = tn * 128;
  const int w = tid >> 6, l = tid & 63, lg = l >> 4, lr = l & 15;
  const int wr = w >> 1, wc = w & 1;
  const int srow = tid >> 2, scol = (tid & 3) * 8;

  f32x4 acc[4][4] = {};

  for (int kt = 0; kt < 32; ++kt) {
    const int k0 = kt * 32;
    uint4 ra[2], rb[2], ral[2], rbl[2];
#pragma unroll
    for (int it = 0; it < 2; ++it) {
      const int row = it * 64 + srow;
      size_t ga = (size_t)(m0 + row) * 1024 + k0 + scol;
      size_t gb = (size_t)(n0 + row) * 1024 + k0 + scol;
      ra[it] = *reinterpret_cast<const uint4*>(Ah + ga);
      rb[it] = *reinterpret_cast<const uint4*>(Bh + gb);
      if (SPLIT) {
        ral[it] = *reinterpret_cast<const uint4*>(Al + ga);
        rbl[it] = *reinterpret_cast<const uint4*>(Bl + gb);
      }
    }
    __syncthreads();
#pragma unroll
    for (int it = 0; it < 2; ++it) {
      const int eo = (it * 256 + tid) * 8;
      *reinterpret_cast<uint4*>(Ahs + eo) = ra[it];
      *reinterpret_cast<uint4*>(Bhs + eo) = rb[it];
      if (SPLIT) {
        *reinterpret_cast<uint4*>(Als + eo) = ral[it];
        *reinterpret_cast<uint4*>(Bls + eo) = rbl[it];
      }
    }
    __syncthreads();

    bf16x8 fa[4], fb[4], fal[4], fbl[4];
#pragma unroll
    for (int i = 0; i < 4; ++i) {
      fa[i] = ldb8(Ahs + (wr * 64 + i * 16 + lr) * 32 + lg * 8);
      fb[i] = ldb8(Bhs + (wc * 64 + i * 16 + lr) * 32 + lg * 8);
      if (SPLIT) {
        fal[i] = ldb8(Als + (wr * 64 + i * 16 + lr) * 32 + lg * 8);
        fbl[i] = ldb8(Bls + (wc * 64 + i * 16 + lr) * 32 + lg * 8);
      }
    }
#pragma unroll
    for (int i = 0; i < 4; ++i)
#pragma unroll
      for (int j = 0; j < 4; ++j) {
        acc[i][j] = MFMA16(fa[i], fb[j], acc[i][j]);
        if (SPLIT) {
          acc[i][j] = MFMA16(fa[i], fbl[j], acc[i][j]);
          acc[i][j] = MFMA16(fal[i], fb[j], acc[i][j]);
        }
      }
    __syncthreads();
  }

#pragma unroll
  for (int i = 0; i < 4; ++i) {
    const int mrow = m0 + wr * 64 + i * 16 + lg * 4;
#pragma unroll
    for (int j = 0; j < 4; ++j) {
      const int ncol = n0 + wc * 64 + j * 16 + lr;
      const float bv = bias[ncol];
#pragma unroll
      for (int r = 0; r < 4; ++r) {
        const int m = mrow + r;
        const float v = acc[i][j][r] + bv;
        if (MODE == 2) {
          out_f[(size_t)m * 1024 + ncol] = v;
        } else {
          const int bb = m >> 11, s = m & 2047, hh = ncol >> 6, d = ncol & 63;
          if (MODE == 0) {
            const size_t off = ((size_t)(bb * 16 + hh) * 2048 + s) * 64 + d;
            const unsigned short hv = f2bf(v);
            out_hi[off] = hv;
            out_lo[off] = f2bf(v - bf2f(hv));
          } else {
            out_hi[((size_t)(bb * 16 + hh) * 64 + d) * 2048 + s] = f2bf(v);
          }
        }
      }
    }
  }
}

// ---------------- fused attention, single pass ----------------
// Writes UNNORMALIZED p = exp(l - 16) to attn_out (fp32), accumulates row sums
// (scale = 1/s stored for the fixup kernel), PV with unnormalized p scaled by
// 1/s in the epilogue. Everything in log2 domain: one v_exp_f32 per logit.
__global__ __launch_bounds__(256) void attn_kernel(
    const unsigned short* __restrict__ qh_hi, const unsigned short* __restrict__ qh_lo,
    const unsigned short* __restrict__ kh_hi, const unsigned short* __restrict__ kh_lo,
    const unsigned short* __restrict__ vT,
    const float* __restrict__ rel_bias, const unsigned short* __restrict__ mb,
    float* __restrict__ attn_out, unsigned short* __restrict__ o_bf,
    float* __restrict__ scal) {
  __shared__ float rb2[2112];
  __shared__ __align__(16) unsigned short khs_hi[64 * 64];  // XOR-swizzled K tile (hi)
  __shared__ __align__(16) unsigned short khs_lo[64 * 64];  // XOR-swizzled K tile (lo)
  __shared__ __align__(16) unsigned short p_lds[64 * 72];   // stride 72: free 2-way only

  const int bh = blockIdx.x >> 5, qt = blockIdx.x & 31;
  const int b = bh >> 4, h = bh & 15;
  const int q0 = qt * 64;
  const int tid = threadIdx.x;
  const int w = tid >> 6, l = tid & 63, lg = l >> 4, lr = l & 15;

  // rel bias in log2 domain with the -16 shift folded in
  for (int t = tid; t < 2112; t += 256)
    rb2[t] = rel_bias[(q0 + t) * 16 + h] * LOG2E - 16.0f * LOG2E;

  const size_t bh_off = (size_t)bh * 2048 * 64;
  const unsigned short* qhh = qh_hi + bh_off;
  const unsigned short* qhl = qh_lo + bh_off;
  const char* khh = (const char*)(kh_hi + bh_off);
  const char* khl = (const char*)(kh_lo + bh_off);
  const unsigned short* vTb = vT + bh_off;
  const unsigned short* mbb = mb + (size_t)b * 2048 * 2048;
  float* attn_bh = attn_out + (size_t)bh * 2048 * 2048;

  bf16x8 qfh[2], qfl[2];
  {
    const size_t qrow = (size_t)(q0 + w * 16 + lr) * 64;
    qfh[0] = ldb8(qhh + qrow + lg * 8);
    qfh[1] = ldb8(qhh + qrow + 32 + lg * 8);
    qfl[0] = ldb8(qhl + qrow + lg * 8);
    qfl[1] = ldb8(qhl + qrow + 32 + lg * 8);
  }

  const int qbase = w * 16 + lg * 4;  // C/D row base within the 64-row tile
  const float c1 = 0.125f * LOG2E;
  float sacc[4] = {0.f, 0.f, 0.f, 0.f};
  f32x4 acc_o[4] = {};

  // staging geometry: element e (16B unit) -> row e>>3, colb (e&7)<<4, XOR-swizzled src
  const int e0 = w * 2 * 64 + l;  // first chunk element for this lane

  for (int kt = 0; kt < 32; ++kt) {
    __syncthreads();  // previous tile fully consumed (also covers rb2 on kt=0)
    // ---- stage K tile (hi+lo), swizzled global source -> linear LDS dest ----
#pragma unroll
    for (int cc = 0; cc < 2; ++cc) {
      const int e = e0 + cc * 64;
      const int row = e >> 3, colb = (e & 7) << 4;
      const int srcb = (row << 7) + (colb ^ ((row & 7) << 4));
      const size_t gb = (size_t)kt * 8192 + srcb;
      gload_lds16(khh + gb, (char*)khs_hi + e * 16);
      gload_lds16(khl + gb, (char*)khs_lo + e * 16);
    }
    // ---- prefetch V fragments (latency hides under the stage-drain barrier) ----
    bf16x8 vf[4][2];
#pragma unroll
    for (int n = 0; n < 4; ++n)
#pragma unroll
      for (int j = 0; j < 2; ++j)
        vf[n][j] = ldb8(vTb + (size_t)(n * 16 + lr) * 2048 + kt * 64 + j * 32 + lg * 8);
    __syncthreads();  // K tile staged (compiler drains vmcnt before s_barrier)

    // ---- QK^T + logits + p ----
#pragma unroll
    for (int c = 0; c < 4; ++c) {
      const int rowk = c * 16 + lr;
      f32x4 acc = {};
#pragma unroll
      for (int kk = 0; kk < 2; ++kk) {
        const int off = (rowk << 7) + (((kk << 6) + (lg << 4)) ^ ((rowk & 7) << 4));
        bf16x8 kfh = ldb8((const unsigned short*)((const char*)khs_hi + off));
        bf16x8 kfl = ldb8((const unsigned short*)((const char*)khs_lo + off));
        acc = MFMA16(qfh[kk], kfh, acc);
        acc = MFMA16(qfh[kk], kfl, acc);
        acc = MFMA16(qfl[kk], kfh, acc);
      }
      const int kc = kt * 64 + c * 16 + lr;
#pragma unroll
      for (int r = 0; r < 4; ++r) {
        const int qr = q0 + qbase + r;
        const float mbf = bf2f(mbb[(size_t)qr * 2048 + kc]);
        const float l2 = fmaf(acc[r], c1, rb2[qbase + r - kc + 2047]) + mbf;
        const float p = EXP2F(l2);
        attn_bh[(size_t)qr * 2048 + kc] = p;
        sacc[r] += p;
        p_lds[(qbase + r) * 72 + c * 16 + lr] = f2bf(p);
      }
    }

    // ---- PV (p rows are wave-local: no barrier needed, lgkmcnt ordering only) ----
    bf16x8 pf0 = ldb8(p_lds + (w * 16 + lr) * 72 + lg * 8);
    bf16x8 pf1 = ldb8(p_lds + (w * 16 + lr) * 72 + 32 + lg * 8);
#pragma unroll
    for (int n = 0; n < 4; ++n) {
      acc_o[n] = MFMA16(pf0, vf[n][0], acc_o[n]);
      acc_o[n] = MFMA16(pf1, vf[n][1], acc_o[n]);
    }
  }

  // ---- row-sum reduce over lr (cols split across 16 lanes) ----
  float inv_s[4];
#pragma unroll
  for (int r = 0; r < 4; ++r) {
    float s = sacc[r];
    s += __shfl_xor(s, 1);
    s += __shfl_xor(s, 2);
    s += __shfl_xor(s, 4);
    s += __shfl_xor(s, 8);
    inv_s[r] = 1.0f / s;
    if (lr == 0) scal[(size_t)bh * 2048 + q0 + qbase + r] = inv_s[r];
  }

  // ---- epilogue: per-head context in [b,s,h,d] as bf16, scaled by 1/s ----
#pragma unroll
  for (int n = 0; n < 4; ++n)
#pragma unroll
    for (int r = 0; r < 4; ++r) {
      const int qr = q0 + qbase + r;
      const int d = n * 16 + lr;
      o_bf[((size_t)(b * 2048 + qr) * 16 + h) * 64 + d] = f2bf(acc_o[n][r] * inv_s[r]);
    }
}

// ---------------- attn normalization fixup: attn[row,:] *= scal[row] ----------------
__global__ __launch_bounds__(256) void scale_kernel(float* __restrict__ attn,
                                                    const float* __restrict__ scal) {
  const long long nt = 33554432LL;  // float4 count (2*16*2048*2048 / 4)
  const long long stride = (long long)gridDim.x * 256;
  for (long long i = (long long)blockIdx.x * 256 + threadIdx.x; i < nt; i += stride) {
    float4 v = reinterpret_cast<float4*>(attn)[i];
    const float s = scal[i >> 9];  // 512 float4 per row
    v.x *= s; v.y *= s; v.z *= s; v.w *= s;
    reinterpret_cast<float4*>(attn)[i] = v;
  }
}

// ---------------- host ----------------
extern "C" void kernel_launch(void* const* d_in, const int* in_sizes, int n_in,
                              void* d_out, int out_size, void* d_ws, size_t ws_size,
                              hipStream_t stream) {
  const float* q = (const float*)d_in[0];
  const float* k = (const float*)d_in[1];
  const float* v = (const float*)d_in[2];
  const float* mask = (const float*)d_in[3];
  const float* wq_w = (const float*)d_in[4];
  const float* wq_b = (const float*)d_in[5];
  const float* wk_w = (const float*)d_in[6];
  const float* wk_b = (const float*)d_in[7];
  const float* wv_w = (const float*)d_in[8];
  const float* wv_b = (const float*)d_in[9];
  const float* dw = (const float*)d_in[10];
  const float* db = (const float*)d_in[11];
  const float* rel = (const float*)d_in[12];

  char* ws = (char*)d_ws;
  unsigned short* q_hi = (unsigned short*)(ws + 0);
  unsigned short* q_lo = (unsigned short*)(ws + 8388608);
  unsigned short* k_hi = (unsigned short*)(ws + 16777216);
  unsigned short* k_lo = (unsigned short*)(ws + 25165824);
  unsigned short* v_bf = (unsigned short*)(ws + 33554432);
  unsigned short* wq_hi = (unsigned short*)(ws + 41943040);
  unsigned short* wq_lo = (unsigned short*)(ws + 44040192);
  unsigned short* wk_hi = (unsigned short*)(ws + 46137344);
  unsigned short* wk_lo = (unsigned short*)(ws + 48234496);
  unsigned short* wv_bf = (unsigned short*)(ws + 50331648);
  unsigned short* dw_bf = (unsigned short*)(ws + 52428800);
  unsigned short* qh_hi = (unsigned short*)(ws + 54525952);
  unsigned short* qh_lo = (unsigned short*)(ws + 62914560);
  unsigned short* kh_hi = (unsigned short*)(ws + 71303168);
  unsigned short* kh_lo = (unsigned short*)(ws + 79691776);
  unsigned short* vhT  = (unsigned short*)(ws + 88080384);
  unsigned short* o_bf = (unsigned short*)(ws + 96468992);
  float* scal          = (float*)(ws + 104857600);
  unsigned short* mb   = (unsigned short*)(ws + 105381888);

  float* out = (float*)d_out;
  float* attn_out = out + 4194304;

  // fp32 -> bf16 (split where the logits path needs precision)
  prep_kernel<<<4096, 256, 0, stream>>>(q, q_hi, q_lo, 1048576);
  prep_kernel<<<4096, 256, 0, stream>>>(k, k_hi, k_lo, 1048576);
  prep_kernel<<<4096, 256, 0, stream>>>(v, v_bf, nullptr, 1048576);
  prep_kernel<<<1024, 256, 0, stream>>>(wq_w, wq_hi, wq_lo, 262144);
  prep_kernel<<<1024, 256, 0, stream>>>(wk_w, wk_hi, wk_lo, 262144);
  prep_kernel<<<1024, 256, 0, stream>>>(wv_w, wv_bf, nullptr, 262144);
  prep_kernel<<<1024, 256, 0, stream>>>(dw, dw_bf, nullptr, 262144);
  prep_mask_kernel<<<8192, 256, 0, stream>>>(mask, mb, 2097152);

  // projections
  gemm_kernel<0><<<256, 256, 0, stream>>>(q_hi, q_lo, wq_hi, wq_lo, wq_b, qh_hi, qh_lo, nullptr);
  gemm_kernel<0><<<256, 256, 0, stream>>>(k_hi, k_lo, wk_hi, wk_lo, wk_b, kh_hi, kh_lo, nullptr);
  gemm_kernel<1><<<256, 256, 0, stream>>>(v_bf, nullptr, wv_bf, nullptr, wv_b, vhT, nullptr, nullptr);

  // fused attention (unnormalized attn + per-head context + row scales)
  attn_kernel<<<1024, 256, 0, stream>>>(qh_hi, qh_lo, kh_hi, kh_lo, vhT, rel, mb, attn_out, o_bf, scal);

  // normalization fixup (pure BW)
  scale_kernel<<<8192, 256, 0, stream>>>(attn_out, scal);

  // output dense projection
  gemm_kernel<2><<<256, 256, 0, stream>>>(o_bf, nullptr, dw_bf, nullptr, db, nullptr, nullptr, out);
}

// Round 3
// 770.332 us; speedup vs baseline: 1.8827x; 1.1392x over previous
//
#include <hip/hip_runtime.h>

typedef __bf16 bf16x8 __attribute__((ext_vector_type(8)));
typedef float f32x4 __attribute__((ext_vector_type(4)));
typedef unsigned short u16x8 __attribute__((ext_vector_type(8)));
typedef unsigned int u32;

#define MFMA16(a, b, c) __builtin_amdgcn_mfma_f32_16x16x32_bf16(a, b, c, 0, 0, 0)

#if __has_builtin(__builtin_amdgcn_exp2f)
#define EXP2F(x) __builtin_amdgcn_exp2f(x)
#else
#define EXP2F(x) exp2f(x)
#endif

#define LOG2E 1.44269504088896340736f

__device__ __forceinline__ unsigned short f2bf(float x) {
  unsigned u = __float_as_uint(x);
  u += 0x7FFF + ((u >> 16) & 1);   // round-to-nearest-even
  return (unsigned short)(u >> 16);
}
__device__ __forceinline__ float bf2f(unsigned short h) {
  return __uint_as_float(((unsigned)h) << 16);
}
__device__ __forceinline__ bf16x8 ldb8(const unsigned short* p) {
  return *reinterpret_cast<const bf16x8*>(p);
}
__device__ __forceinline__ u16x8 ldu8(const unsigned short* p) {
  return *reinterpret_cast<const u16x8*>(p);
}
__device__ __forceinline__ void gload_lds16(const void* g, void* lds) {
  __builtin_amdgcn_global_load_lds(
      (const __attribute__((address_space(1))) u32*)g,
      (__attribute__((address_space(3))) u32*)lds, 16, 0, 0);
}

// ---------------- fp32 -> bf16 (hi, optional lo residual) ----------------
__global__ __launch_bounds__(256) void prep_kernel(const float* __restrict__ src,
                                                   unsigned short* __restrict__ hi,
                                                   unsigned short* __restrict__ lo,
                                                   int n4) {
  int i = blockIdx.x * 256 + threadIdx.x;
  if (i >= n4) return;
  float4 x = reinterpret_cast<const float4*>(src)[i];
  unsigned short h0 = f2bf(x.x), h1 = f2bf(x.y), h2 = f2bf(x.z), h3 = f2bf(x.w);
  reinterpret_cast<ushort4*>(hi)[i] = make_ushort4(h0, h1, h2, h3);
  if (lo) {
    reinterpret_cast<ushort4*>(lo)[i] =
        make_ushort4(f2bf(x.x - bf2f(h0)), f2bf(x.y - bf2f(h1)),
                     f2bf(x.z - bf2f(h2)), f2bf(x.w - bf2f(h3)));
  }
}

// ---------------- mask -> permuted bf16( mask * -1e9 * log2e ) ----------------
// Layout: [(b*32+qt)*32+kt][lane 0..255][idx 0..15] u16, idx = c*4+r so an attn
// lane fetches its 16 fragment-ordered mask values as two dwordx4 loads.
__global__ __launch_bounds__(256) void prep_mask_perm(const float* __restrict__ src,
                                                      unsigned short* __restrict__ dst) {
  const int blk = blockIdx.x;               // (b*32+qt)*32 + kt
  const int kt = blk & 31, bq = blk >> 5;
  const int b = bq >> 5, qt = bq & 31;
  const int lane = threadIdx.x;
  const int w = lane >> 6, lg = (lane >> 4) & 3, lr = lane & 15;
  const int q0 = qt * 64;
  const float cs = -1e9f * LOG2E;
  unsigned short vals[16];
#pragma unroll
  for (int c = 0; c < 4; ++c)
#pragma unroll
    for (int r = 0; r < 4; ++r) {
      const int qr = q0 + w * 16 + lg * 4 + r;
      const int kc = kt * 64 + c * 16 + lr;
      vals[c * 4 + r] = f2bf(src[((size_t)b * 2048 + qr) * 2048 + kc] * cs);
    }
  uint4* out = reinterpret_cast<uint4*>(dst) + ((size_t)blk * 256 + lane) * 2;
  out[0] = *reinterpret_cast<uint4*>(&vals[0]);
  out[1] = *reinterpret_cast<uint4*>(&vals[8]);
}

// ---------------- GEMM: y[m,n] = sum_k A[m,k]*B[n,k] + bias[n] ----------------
// MODE 0: split inputs, output split bf16 pair, head-split [b,h,s,d]
// MODE 1: single inputs, output bf16 transposed per head [b,h,d,s]
// MODE 2: single inputs, output fp32 row-major [m,n]
template <int MODE>
__global__ __launch_bounds__(256) void gemm_kernel(
    const unsigned short* __restrict__ Ah, const unsigned short* __restrict__ Al,
    const unsigned short* __restrict__ Bh, const unsigned short* __restrict__ Bl,
    const float* __restrict__ bias,
    unsigned short* __restrict__ out_hi, unsigned short* __restrict__ out_lo,
    float* __restrict__ out_f) {
  constexpr bool SPLIT = (MODE == 0);
  __shared__ __align__(16) unsigned short Ahs[128 * 32];
  __shared__ __align__(16) unsigned short Bhs[128 * 32];
  __shared__ __align__(16) unsigned short Als[128 * 32];
  __shared__ __align__(16) unsigned short Bls[128 * 32];

  const int tid = threadIdx.x;
  const int tm = blockIdx.x & 31, tn = blockIdx.x >> 5;
  const int m0 = tm * 128, n0 = tn * 128;
  const int w = tid >> 6, l = tid & 63, lg = l >> 4, lr = l & 15;
  const int wr = w >> 1, wc = w & 1;
  const int srow = tid >> 2, scol = (tid & 3) * 8;

  f32x4 acc[4][4] = {};

  for (int kt = 0; kt < 32; ++kt) {
    const int k0 = kt * 32;
    uint4 ra[2], rb[2], ral[2], rbl[2];
#pragma unroll
    for (int it = 0; it < 2; ++it) {
      const int row = it * 64 + srow;
      size_t ga = (size_t)(m0 + row) * 1024 + k0 + scol;
      size_t gb = (size_t)(n0 + row) * 1024 + k0 + scol;
      ra[it] = *reinterpret_cast<const uint4*>(Ah + ga);
      rb[it] = *reinterpret_cast<const uint4*>(Bh + gb);
      if (SPLIT) {
        ral[it] = *reinterpret_cast<const uint4*>(Al + ga);
        rbl[it] = *reinterpret_cast<const uint4*>(Bl + gb);
      }
    }
    __syncthreads();
#pragma unroll
    for (int it = 0; it < 2; ++it) {
      const int eo = (it * 256 + tid) * 8;
      *reinterpret_cast<uint4*>(Ahs + eo) = ra[it];
      *reinterpret_cast<uint4*>(Bhs + eo) = rb[it];
      if (SPLIT) {
        *reinterpret_cast<uint4*>(Als + eo) = ral[it];
        *reinterpret_cast<uint4*>(Bls + eo) = rbl[it];
      }
    }
    __syncthreads();

    bf16x8 fa[4], fb[4], fal[4], fbl[4];
#pragma unroll
    for (int i = 0; i < 4; ++i) {
      fa[i] = ldb8(Ahs + (wr * 64 + i * 16 + lr) * 32 + lg * 8);
      fb[i] = ldb8(Bhs + (wc * 64 + i * 16 + lr) * 32 + lg * 8);
      if (SPLIT) {
        fal[i] = ldb8(Als + (wr * 64 + i * 16 + lr) * 32 + lg * 8);
        fbl[i] = ldb8(Bls + (wc * 64 + i * 16 + lr) * 32 + lg * 8);
      }
    }
#pragma unroll
    for (int i = 0; i < 4; ++i)
#pragma unroll
      for (int j = 0; j < 4; ++j) {
        acc[i][j] = MFMA16(fa[i], fb[j], acc[i][j]);
        if (SPLIT) {
          acc[i][j] = MFMA16(fa[i], fbl[j], acc[i][j]);
          acc[i][j] = MFMA16(fal[i], fb[j], acc[i][j]);
        }
      }
    __syncthreads();
  }

#pragma unroll
  for (int i = 0; i < 4; ++i) {
    const int mrow = m0 + wr * 64 + i * 16 + lg * 4;
#pragma unroll
    for (int j = 0; j < 4; ++j) {
      const int ncol = n0 + wc * 64 + j * 16 + lr;
      const float bv = bias[ncol];
#pragma unroll
      for (int r = 0; r < 4; ++r) {
        const int m = mrow + r;
        const float v = acc[i][j][r] + bv;
        if (MODE == 2) {
          out_f[(size_t)m * 1024 + ncol] = v;
        } else {
          const int bb = m >> 11, s = m & 2047, hh = ncol >> 6, d = ncol & 63;
          if (MODE == 0) {
            const size_t off = ((size_t)(bb * 16 + hh) * 2048 + s) * 64 + d;
            const unsigned short hv = f2bf(v);
            out_hi[off] = hv;
            out_lo[off] = f2bf(v - bf2f(hv));
          } else {
            out_hi[((size_t)(bb * 16 + hh) * 64 + d) * 2048 + s] = f2bf(v);
          }
        }
      }
    }
  }
}

// ---------------- attention pass 1: QK^T + exp + row sums + PV ----------------
// No attn store. Writes o_bf (per-head context, normalized) and scal = 1/s.
__global__ __launch_bounds__(256) void attn_pv_kernel(
    const unsigned short* __restrict__ qh_hi, const unsigned short* __restrict__ qh_lo,
    const unsigned short* __restrict__ kh_hi, const unsigned short* __restrict__ kh_lo,
    const unsigned short* __restrict__ vT,
    const float* __restrict__ rel_bias, const unsigned short* __restrict__ mperm,
    unsigned short* __restrict__ o_bf, float* __restrict__ scal) {
  __shared__ float rb2[2112];
  __shared__ __align__(16) unsigned short khs_hi[64 * 64];
  __shared__ __align__(16) unsigned short khs_lo[64 * 64];
  __shared__ __align__(16) unsigned short p_lds[64 * 76];

  const int bid = blockIdx.x;
  const int wg = ((bid & 7) << 7) | (bid >> 3);   // XCD-chunked: 4 bh per XCD
  const int bh = wg >> 5, qt = wg & 31;
  const int b = bh >> 4, h = bh & 15;
  const int q0 = qt * 64;
  const int tid = threadIdx.x;
  const int w = tid >> 6, l = tid & 63, lg = l >> 4, lr = l & 15;

  for (int t = tid; t < 2112; t += 256)
    rb2[t] = rel_bias[(q0 + t) * 16 + h] * LOG2E - 16.0f * LOG2E;

  const size_t bh_off = (size_t)bh * 2048 * 64;
  const unsigned short* qhh = qh_hi + bh_off;
  const unsigned short* qhl = qh_lo + bh_off;
  const char* khh = (const char*)(kh_hi + bh_off);
  const char* khl = (const char*)(kh_lo + bh_off);
  const unsigned short* vTb = vT + bh_off;
  const unsigned short* mpb =
      mperm + (((size_t)(b * 32 + qt) * 32) * 256 + tid) * 16;

  bf16x8 qfh[2], qfl[2];
  {
    const size_t qrow = (size_t)(q0 + w * 16 + lr) * 64;
    qfh[0] = ldb8(qhh + qrow + lg * 8);
    qfh[1] = ldb8(qhh + qrow + 32 + lg * 8);
    qfl[0] = ldb8(qhl + qrow + lg * 8);
    qfl[1] = ldb8(qhl + qrow + 32 + lg * 8);
  }

  const int qbase = w * 16 + lg * 4;
  const float c1 = 0.125f * LOG2E;
  float sacc[4] = {0.f, 0.f, 0.f, 0.f};
  f32x4 acc_o[4] = {};
  const int e0 = w * 2 * 64 + l;

  for (int kt = 0; kt < 32; ++kt) {
    __syncthreads();  // previous tile consumed (covers rb2 on kt=0)
#pragma unroll
    for (int cc = 0; cc < 2; ++cc) {
      const int e = e0 + cc * 64;
      const int row = e >> 3, colb = (e & 7) << 4;
      const int srcb = (row << 7) + (colb ^ ((row & 7) << 4));
      const size_t gb = (size_t)kt * 8192 + srcb;
      gload_lds16(khh + gb, (char*)khs_hi + e * 16);
      gload_lds16(khl + gb, (char*)khs_lo + e * 16);
    }
    // prefetch mask (2 dwordx4) + V fragments
    u16x8 m0v = ldu8(mpb + (size_t)kt * 256 * 16);
    u16x8 m1v = ldu8(mpb + (size_t)kt * 256 * 16 + 8);
    bf16x8 vf[4][2];
#pragma unroll
    for (int n = 0; n < 4; ++n)
#pragma unroll
      for (int j = 0; j < 2; ++j)
        vf[n][j] = ldb8(vTb + (size_t)(n * 16 + lr) * 2048 + kt * 64 + j * 32 + lg * 8);
    __syncthreads();  // K tile staged

#pragma unroll
    for (int c = 0; c < 4; ++c) {
      const int rowk = c * 16 + lr;
      f32x4 acc = {};
#pragma unroll
      for (int kk = 0; kk < 2; ++kk) {
        const int off = (rowk << 7) + (((kk << 6) + (lg << 4)) ^ ((rowk & 7) << 4));
        bf16x8 kfh = ldb8((const unsigned short*)((const char*)khs_hi + off));
        bf16x8 kfl = ldb8((const unsigned short*)((const char*)khs_lo + off));
        acc = MFMA16(qfh[kk], kfh, acc);
        acc = MFMA16(qfh[kk], kfl, acc);
        acc = MFMA16(qfl[kk], kfh, acc);
      }
      const int kc = kt * 64 + c * 16 + lr;
#pragma unroll
      for (int r = 0; r < 4; ++r) {
        const float mbf = bf2f((c < 2) ? (unsigned short)m0v[(c & 1) * 4 + r]
                                       : (unsigned short)m1v[(c & 1) * 4 + r]);
        const float l2 = fmaf(acc[r], c1, rb2[qbase + r - kc + 2047]) + mbf;
        const float p = EXP2F(l2);
        sacc[r] += p;
        p_lds[(qbase + r) * 76 + c * 16 + lr] = f2bf(p);
      }
    }

    // PV: p rows are wave-local, lgkmcnt ordering only
    bf16x8 pf0 = ldb8(p_lds + (w * 16 + lr) * 76 + lg * 8);
    bf16x8 pf1 = ldb8(p_lds + (w * 16 + lr) * 76 + 32 + lg * 8);
#pragma unroll
    for (int n = 0; n < 4; ++n) {
      acc_o[n] = MFMA16(pf0, vf[n][0], acc_o[n]);
      acc_o[n] = MFMA16(pf1, vf[n][1], acc_o[n]);
    }
  }

  float inv_s[4];
#pragma unroll
  for (int r = 0; r < 4; ++r) {
    float s = sacc[r];
    s += __shfl_xor(s, 1);
    s += __shfl_xor(s, 2);
    s += __shfl_xor(s, 4);
    s += __shfl_xor(s, 8);
    inv_s[r] = 1.0f / s;
    if (lr == 0) scal[(size_t)bh * 2048 + q0 + qbase + r] = inv_s[r];
  }

#pragma unroll
  for (int n = 0; n < 4; ++n)
#pragma unroll
    for (int r = 0; r < 4; ++r) {
      const int qr = q0 + qbase + r;
      const int d = n * 16 + lr;
      o_bf[((size_t)(b * 2048 + qr) * 16 + h) * 64 + d] = f2bf(acc_o[n][r] * inv_s[r]);
    }
}

// ---------------- attention pass 2: recompute QK^T, write normalized attn ----------------
__global__ __launch_bounds__(256) void attn_write_kernel(
    const unsigned short* __restrict__ qh_hi, const unsigned short* __restrict__ qh_lo,
    const unsigned short* __restrict__ kh_hi, const unsigned short* __restrict__ kh_lo,
    const float* __restrict__ rel_bias, const unsigned short* __restrict__ mperm,
    const float* __restrict__ scal, float* __restrict__ attn_out) {
  __shared__ float rb2[2112];
  __shared__ __align__(16) unsigned short khs_hi[64 * 64];
  __shared__ __align__(16) unsigned short khs_lo[64 * 64];
  __shared__ __align__(16) float p32[64 * 68];

  const int bid = blockIdx.x;
  const int wg = ((bid & 7) << 7) | (bid >> 3);
  const int bh = wg >> 5, qt = wg & 31;
  const int b = bh >> 4, h = bh & 15;
  const int q0 = qt * 64;
  const int tid = threadIdx.x;
  const int w = tid >> 6, l = tid & 63, lg = l >> 4, lr = l & 15;

  for (int t = tid; t < 2112; t += 256)
    rb2[t] = rel_bias[(q0 + t) * 16 + h] * LOG2E - 16.0f * LOG2E;

  const size_t bh_off = (size_t)bh * 2048 * 64;
  const unsigned short* qhh = qh_hi + bh_off;
  const unsigned short* qhl = qh_lo + bh_off;
  const char* khh = (const char*)(kh_hi + bh_off);
  const char* khl = (const char*)(kh_lo + bh_off);
  const unsigned short* mpb =
      mperm + (((size_t)(b * 32 + qt) * 32) * 256 + tid) * 16;
  float* attn_bh = attn_out + (size_t)bh * 2048 * 2048;

  bf16x8 qfh[2], qfl[2];
  {
    const size_t qrow = (size_t)(q0 + w * 16 + lr) * 64;
    qfh[0] = ldb8(qhh + qrow + lg * 8);
    qfh[1] = ldb8(qhh + qrow + 32 + lg * 8);
    qfl[0] = ldb8(qhl + qrow + lg * 8);
    qfl[1] = ldb8(qhl + qrow + 32 + lg * 8);
  }

  const int qbase = w * 16 + lg * 4;
  const float c1 = 0.125f * LOG2E;
  // 1/s for this lane's 4 rows (written by attn_pv)
  float4 inv4 = *reinterpret_cast<const float4*>(scal + (size_t)bh * 2048 + q0 + qbase);
  const float invs[4] = {inv4.x, inv4.y, inv4.z, inv4.w};

  // store geometry: thread covers row w*16+(tl>>2), cols (tl&3)*16 .. +15
  const int tl = l;
  const int srow = w * 16 + (tl >> 2);
  const int scb = (tl & 3) * 16;
  const int e0 = w * 2 * 64 + l;

  for (int kt = 0; kt < 32; ++kt) {
    __syncthreads();
#pragma unroll
    for (int cc = 0; cc < 2; ++cc) {
      const int e = e0 + cc * 64;
      const int row = e >> 3, colb = (e & 7) << 4;
      const int srcb = (row << 7) + (colb ^ ((row & 7) << 4));
      const size_t gb = (size_t)kt * 8192 + srcb;
      gload_lds16(khh + gb, (char*)khs_hi + e * 16);
      gload_lds16(khl + gb, (char*)khs_lo + e * 16);
    }
    u16x8 m0v = ldu8(mpb + (size_t)kt * 256 * 16);
    u16x8 m1v = ldu8(mpb + (size_t)kt * 256 * 16 + 8);
    __syncthreads();

#pragma unroll
    for (int c = 0; c < 4; ++c) {
      const int rowk = c * 16 + lr;
      f32x4 acc = {};
#pragma unroll
      for (int kk = 0; kk < 2; ++kk) {
        const int off = (rowk << 7) + (((kk << 6) + (lg << 4)) ^ ((rowk & 7) << 4));
        bf16x8 kfh = ldb8((const unsigned short*)((const char*)khs_hi + off));
        bf16x8 kfl = ldb8((const unsigned short*)((const char*)khs_lo + off));
        acc = MFMA16(qfh[kk], kfh, acc);
        acc = MFMA16(qfh[kk], kfl, acc);
        acc = MFMA16(qfl[kk], kfh, acc);
      }
      const int kc = kt * 64 + c * 16 + lr;
#pragma unroll
      for (int r = 0; r < 4; ++r) {
        const float mbf = bf2f((c < 2) ? (unsigned short)m0v[(c & 1) * 4 + r]
                                       : (unsigned short)m1v[(c & 1) * 4 + r]);
        const float l2 = fmaf(acc[r], c1, rb2[qbase + r - kc + 2047]) + mbf;
        p32[(qbase + r) * 68 + c * 16 + lr] = EXP2F(l2) * invs[r];
      }
    }

    // wave-local vectorized store (rows 16w..16w+15 written by this wave)
    float* arow = attn_bh + (size_t)(q0 + srow) * 2048 + kt * 64 + scb;
#pragma unroll
    for (int i = 0; i < 4; ++i)
      *reinterpret_cast<float4*>(arow + i * 4) =
          *reinterpret_cast<const float4*>(&p32[srow * 68 + scb + i * 4]);
  }
}

// ---------------- host ----------------
extern "C" void kernel_launch(void* const* d_in, const int* in_sizes, int n_in,
                              void* d_out, int out_size, void* d_ws, size_t ws_size,
                              hipStream_t stream) {
  const float* q = (const float*)d_in[0];
  const float* k = (const float*)d_in[1];
  const float* v = (const float*)d_in[2];
  const float* mask = (const float*)d_in[3];
  const float* wq_w = (const float*)d_in[4];
  const float* wq_b = (const float*)d_in[5];
  const float* wk_w = (const float*)d_in[6];
  const float* wk_b = (const float*)d_in[7];
  const float* wv_w = (const float*)d_in[8];
  const float* wv_b = (const float*)d_in[9];
  const float* dw = (const float*)d_in[10];
  const float* db = (const float*)d_in[11];
  const float* rel = (const float*)d_in[12];

  char* ws = (char*)d_ws;
  unsigned short* q_hi = (unsigned short*)(ws + 0);
  unsigned short* q_lo = (unsigned short*)(ws + 8388608);
  unsigned short* k_hi = (unsigned short*)(ws + 16777216);
  unsigned short* k_lo = (unsigned short*)(ws + 25165824);
  unsigned short* v_bf = (unsigned short*)(ws + 33554432);
  unsigned short* wq_hi = (unsigned short*)(ws + 41943040);
  unsigned short* wq_lo = (unsigned short*)(ws + 44040192);
  unsigned short* wk_hi = (unsigned short*)(ws + 46137344);
  unsigned short* wk_lo = (unsigned short*)(ws + 48234496);
  unsigned short* wv_bf = (unsigned short*)(ws + 50331648);
  unsigned short* dw_bf = (unsigned short*)(ws + 52428800);
  unsigned short* qh_hi = (unsigned short*)(ws + 54525952);
  unsigned short* qh_lo = (unsigned short*)(ws + 62914560);
  unsigned short* kh_hi = (unsigned short*)(ws + 71303168);
  unsigned short* kh_lo = (unsigned short*)(ws + 79691776);
  unsigned short* vhT  = (unsigned short*)(ws + 88080384);
  unsigned short* o_bf = (unsigned short*)(ws + 96468992);
  float* scal          = (float*)(ws + 104857600);
  unsigned short* mperm = (unsigned short*)(ws + 105381888);

  float* out = (float*)d_out;
  float* attn_out = out + 4194304;

  prep_kernel<<<4096, 256, 0, stream>>>(q, q_hi, q_lo, 1048576);
  prep_kernel<<<4096, 256, 0, stream>>>(k, k_hi, k_lo, 1048576);
  prep_kernel<<<4096, 256, 0, stream>>>(v, v_bf, nullptr, 1048576);
  prep_kernel<<<1024, 256, 0, stream>>>(wq_w, wq_hi, wq_lo, 262144);
  prep_kernel<<<1024, 256, 0, stream>>>(wk_w, wk_hi, wk_lo, 262144);
  prep_kernel<<<1024, 256, 0, stream>>>(wv_w, wv_bf, nullptr, 262144);
  prep_kernel<<<1024, 256, 0, stream>>>(dw, dw_bf, nullptr, 262144);
  prep_mask_perm<<<2048, 256, 0, stream>>>(mask, mperm);

  gemm_kernel<0><<<256, 256, 0, stream>>>(q_hi, q_lo, wq_hi, wq_lo, wq_b, qh_hi, qh_lo, nullptr);
  gemm_kernel<0><<<256, 256, 0, stream>>>(k_hi, k_lo, wk_hi, wk_lo, wk_b, kh_hi, kh_lo, nullptr);
  gemm_kernel<1><<<256, 256, 0, stream>>>(v_bf, nullptr, wv_bf, nullptr, wv_b, vhT, nullptr, nullptr);

  attn_pv_kernel<<<1024, 256, 0, stream>>>(qh_hi, qh_lo, kh_hi, kh_lo, vhT, rel, mperm, o_bf, scal);
  attn_write_kernel<<<1024, 256, 0, stream>>>(qh_hi, qh_lo, kh_hi, kh_lo, rel, mperm, scal, attn_out);

  gemm_kernel<2><<<256, 256, 0, stream>>>(o_bf, nullptr, dw_bf, nullptr, db, nullptr, nullptr, out);
}

// Round 4
// 650.953 us; speedup vs baseline: 2.2280x; 1.1834x over previous
//
#include <hip/hip_runtime.h>

typedef _Float16 f16x8 __attribute__((ext_vector_type(8)));
typedef _Float16 f16x4 __attribute__((ext_vector_type(4)));
typedef float f32x4 __attribute__((ext_vector_type(4)));
typedef unsigned short u16x8 __attribute__((ext_vector_type(8)));
typedef unsigned int u32;

#define MFMA16H(a, b, c) __builtin_amdgcn_mfma_f32_16x16x32_f16(a, b, c, 0, 0, 0)

#if __has_builtin(__builtin_amdgcn_exp2f)
#define EXP2F(x) __builtin_amdgcn_exp2f(x)
#else
#define EXP2F(x) exp2f(x)
#endif

#define LOG2E 1.44269504088896340736f
#define SHIFT2 14.0f   // log2-domain shift so unnormalized p fits fp16 comfortably

__device__ __forceinline__ unsigned short f2bf(float x) {
  unsigned u = __float_as_uint(x);
  u += 0x7FFF + ((u >> 16) & 1);   // round-to-nearest-even
  return (unsigned short)(u >> 16);
}
__device__ __forceinline__ float bf2f(unsigned short h) {
  return __uint_as_float(((unsigned)h) << 16);
}
__device__ __forceinline__ f16x8 ldh8(const _Float16* p) {
  return *reinterpret_cast<const f16x8*>(p);
}
__device__ __forceinline__ u16x8 ldu8(const unsigned short* p) {
  return *reinterpret_cast<const u16x8*>(p);
}
__device__ __forceinline__ void gload_lds16(const void* g, void* lds) {
  __builtin_amdgcn_global_load_lds(
      (const __attribute__((address_space(1))) u32*)g,
      (__attribute__((address_space(3))) u32*)lds, 16, 0, 0);
}

// ---------------- fp32 -> fp16 ----------------
__global__ __launch_bounds__(256) void prep_f16(const float* __restrict__ src,
                                                _Float16* __restrict__ dst, int n4) {
  int i = blockIdx.x * 256 + threadIdx.x;
  if (i >= n4) return;
  float4 x = reinterpret_cast<const float4*>(src)[i];
  f16x4 h;
  h[0] = (_Float16)x.x; h[1] = (_Float16)x.y;
  h[2] = (_Float16)x.z; h[3] = (_Float16)x.w;
  reinterpret_cast<f16x4*>(dst)[i] = h;
}

// ---------------- mask -> permuted bf16( mask * -1e9 * log2e ) ----------------
// Layout: [(b*32+qt)*32+kt][lane 0..255][idx 0..15] u16, idx = c*4+r so an attn
// lane fetches its 16 fragment-ordered mask values as two dwordx4 loads.
__global__ __launch_bounds__(256) void prep_mask_perm(const float* __restrict__ src,
                                                      unsigned short* __restrict__ dst) {
  const int blk = blockIdx.x;               // (b*32+qt)*32 + kt
  const int kt = blk & 31, bq = blk >> 5;
  const int b = bq >> 5, qt = bq & 31;
  const int lane = threadIdx.x;
  const int w = lane >> 6, lg = (lane >> 4) & 3, lr = lane & 15;
  const int q0 = qt * 64;
  const float cs = -1e9f * LOG2E;
  unsigned short vals[16];
#pragma unroll
  for (int c = 0; c < 4; ++c)
#pragma unroll
    for (int r = 0; r < 4; ++r) {
      const int qr = q0 + w * 16 + lg * 4 + r;
      const int kc = kt * 64 + c * 16 + lr;
      vals[c * 4 + r] = f2bf(src[((size_t)b * 2048 + qr) * 2048 + kc] * cs);
    }
  uint4* out = reinterpret_cast<uint4*>(dst) + ((size_t)blk * 256 + lane) * 2;
  out[0] = *reinterpret_cast<uint4*>(&vals[0]);
  out[1] = *reinterpret_cast<uint4*>(&vals[8]);
}

// ---------------- GEMM: y[m,n] = sum_k A[m,k]*B[n,k] + bias[n], fp16 in ----------------
// MODE 0: out fp16 head-split [b,h,s,d]
// MODE 1: out fp16 transposed per head [b,h,d,s]
// MODE 2: out fp32 row-major [m,n]
template <int MODE>
__global__ __launch_bounds__(256) void gemm_kernel(
    const _Float16* __restrict__ A, const _Float16* __restrict__ B,
    const float* __restrict__ bias,
    _Float16* __restrict__ out_h, float* __restrict__ out_f) {
  __shared__ __align__(16) _Float16 As[128 * 32];
  __shared__ __align__(16) _Float16 Bs[128 * 32];

  const int tid = threadIdx.x;
  const int tm = blockIdx.x & 31, tn = blockIdx.x >> 5;
  const int m0 = tm * 128, n0 = tn * 128;
  const int w = tid >> 6, l = tid & 63, lg = l >> 4, lr = l & 15;
  const int wr = w >> 1, wc = w & 1;
  const int srow = tid >> 2, scol = (tid & 3) * 8;

  f32x4 acc[4][4] = {};

  for (int kt = 0; kt < 32; ++kt) {
    const int k0 = kt * 32;
    uint4 ra[2], rb[2];
#pragma unroll
    for (int it = 0; it < 2; ++it) {
      const int row = it * 64 + srow;
      ra[it] = *reinterpret_cast<const uint4*>(A + (size_t)(m0 + row) * 1024 + k0 + scol);
      rb[it] = *reinterpret_cast<const uint4*>(B + (size_t)(n0 + row) * 1024 + k0 + scol);
    }
    __syncthreads();
#pragma unroll
    for (int it = 0; it < 2; ++it) {
      const int eo = (it * 256 + tid) * 8;
      *reinterpret_cast<uint4*>(As + eo) = ra[it];
      *reinterpret_cast<uint4*>(Bs + eo) = rb[it];
    }
    __syncthreads();

    f16x8 fa[4], fb[4];
#pragma unroll
    for (int i = 0; i < 4; ++i) {
      fa[i] = ldh8(As + (wr * 64 + i * 16 + lr) * 32 + lg * 8);
      fb[i] = ldh8(Bs + (wc * 64 + i * 16 + lr) * 32 + lg * 8);
    }
#pragma unroll
    for (int i = 0; i < 4; ++i)
#pragma unroll
      for (int j = 0; j < 4; ++j)
        acc[i][j] = MFMA16H(fa[i], fb[j], acc[i][j]);
    __syncthreads();
  }

#pragma unroll
  for (int i = 0; i < 4; ++i) {
    const int mrow = m0 + wr * 64 + i * 16 + lg * 4;
#pragma unroll
    for (int j = 0; j < 4; ++j) {
      const int ncol = n0 + wc * 64 + j * 16 + lr;
      const float bv = bias[ncol];
#pragma unroll
      for (int r = 0; r < 4; ++r) {
        const int m = mrow + r;
        const float v = acc[i][j][r] + bv;
        if (MODE == 2) {
          out_f[(size_t)m * 1024 + ncol] = v;
        } else {
          const int bb = m >> 11, s = m & 2047, hh = ncol >> 6, d = ncol & 63;
          if (MODE == 0)
            out_h[((size_t)(bb * 16 + hh) * 2048 + s) * 64 + d] = (_Float16)v;
          else
            out_h[((size_t)(bb * 16 + hh) * 64 + d) * 2048 + s] = (_Float16)v;
        }
      }
    }
  }
}

// ---------------- attention pass 1: QK^T + exp + row sums + PV ----------------
// p' = 2^(l*log2e - SHIFT2); normalization cancels the shift. Writes o (fp16
// per-head context, normalized) and scal = 1/sum(p') for attn_write.
__global__ __launch_bounds__(256) void attn_pv_kernel(
    const _Float16* __restrict__ qh, const _Float16* __restrict__ kh,
    const _Float16* __restrict__ vT,
    const float* __restrict__ rel_bias, const unsigned short* __restrict__ mperm,
    _Float16* __restrict__ o_h, float* __restrict__ scal) {
  __shared__ float rb2[2112];
  __shared__ __align__(16) _Float16 khs[64 * 64];
  __shared__ __align__(16) _Float16 p_lds[64 * 76];

  const int bid = blockIdx.x;
  const int wg = ((bid & 7) << 7) | (bid >> 3);   // XCD-chunked: 4 bh per XCD
  const int bh = wg >> 5, qt = wg & 31;
  const int b = bh >> 4, h = bh & 15;
  const int q0 = qt * 64;
  const int tid = threadIdx.x;
  const int w = tid >> 6, l = tid & 63, lg = l >> 4, lr = l & 15;

  for (int t = tid; t < 2112; t += 256)
    rb2[t] = rel_bias[(q0 + t) * 16 + h] * LOG2E - SHIFT2;

  const size_t bh_off = (size_t)bh * 2048 * 64;
  const _Float16* qhb = qh + bh_off;
  const char* khb = (const char*)(kh + bh_off);
  const _Float16* vTb = vT + bh_off;
  const unsigned short* mpb =
      mperm + (((size_t)(b * 32 + qt) * 32) * 256 + tid) * 16;

  f16x8 qf[2];
  {
    const size_t qrow = (size_t)(q0 + w * 16 + lr) * 64;
    qf[0] = ldh8(qhb + qrow + lg * 8);
    qf[1] = ldh8(qhb + qrow + 32 + lg * 8);
  }

  const int qbase = w * 16 + lg * 4;
  const float c1 = 0.125f * LOG2E;
  float sacc[4] = {0.f, 0.f, 0.f, 0.f};
  f32x4 acc_o[4] = {};
  const int e0 = w * 2 * 64 + l;

  for (int kt = 0; kt < 32; ++kt) {
    __syncthreads();  // previous tile consumed (covers rb2 on kt=0)
#pragma unroll
    for (int cc = 0; cc < 2; ++cc) {
      const int e = e0 + cc * 64;
      const int row = e >> 3, colb = (e & 7) << 4;
      const int srcb = (row << 7) + (colb ^ ((row & 7) << 4));
      gload_lds16(khb + (size_t)kt * 8192 + srcb, (char*)khs + e * 16);
    }
    // prefetch mask (2 dwordx4) + V fragments
    u16x8 m0v = ldu8(mpb + (size_t)kt * 256 * 16);
    u16x8 m1v = ldu8(mpb + (size_t)kt * 256 * 16 + 8);
    f16x8 vf[4][2];
#pragma unroll
    for (int n = 0; n < 4; ++n)
#pragma unroll
      for (int j = 0; j < 2; ++j)
        vf[n][j] = ldh8(vTb + (size_t)(n * 16 + lr) * 2048 + kt * 64 + j * 32 + lg * 8);
    __syncthreads();  // K tile staged

#pragma unroll
    for (int c = 0; c < 4; ++c) {
      const int rowk = c * 16 + lr;
      f32x4 acc = {};
#pragma unroll
      for (int kk = 0; kk < 2; ++kk) {
        const int off = (rowk << 7) + (((kk << 6) + (lg << 4)) ^ ((rowk & 7) << 4));
        acc = MFMA16H(qf[kk], ldh8((const _Float16*)((const char*)khs + off)), acc);
      }
      const int kc = kt * 64 + c * 16 + lr;
#pragma unroll
      for (int r = 0; r < 4; ++r) {
        const float mbf = bf2f((c < 2) ? (unsigned short)m0v[(c & 1) * 4 + r]
                                       : (unsigned short)m1v[(c & 1) * 4 + r]);
        const float l2 = fmaf(acc[r], c1, rb2[qbase + r - kc + 2047]) + mbf;
        const float p = EXP2F(l2);
        sacc[r] += p;
        p_lds[(qbase + r) * 76 + c * 16 + lr] = (_Float16)p;
      }
    }

    // PV: p rows are wave-local, lgkmcnt ordering only
    f16x8 pf0 = ldh8(p_lds + (w * 16 + lr) * 76 + lg * 8);
    f16x8 pf1 = ldh8(p_lds + (w * 16 + lr) * 76 + 32 + lg * 8);
#pragma unroll
    for (int n = 0; n < 4; ++n) {
      acc_o[n] = MFMA16H(pf0, vf[n][0], acc_o[n]);
      acc_o[n] = MFMA16H(pf1, vf[n][1], acc_o[n]);
    }
  }

  float inv_s[4];
#pragma unroll
  for (int r = 0; r < 4; ++r) {
    float s = sacc[r];
    s += __shfl_xor(s, 1);
    s += __shfl_xor(s, 2);
    s += __shfl_xor(s, 4);
    s += __shfl_xor(s, 8);
    inv_s[r] = 1.0f / s;
    if (lr == 0) scal[(size_t)bh * 2048 + q0 + qbase + r] = inv_s[r];
  }

#pragma unroll
  for (int n = 0; n < 4; ++n)
#pragma unroll
    for (int r = 0; r < 4; ++r) {
      const int qr = q0 + qbase + r;
      const int d = n * 16 + lr;
      o_h[((size_t)(b * 2048 + qr) * 16 + h) * 64 + d] = (_Float16)(acc_o[n][r] * inv_s[r]);
    }
}

// ---------------- attention pass 2: recompute QK^T, write normalized attn ----------------
__global__ __launch_bounds__(256) void attn_write_kernel(
    const _Float16* __restrict__ qh, const _Float16* __restrict__ kh,
    const float* __restrict__ rel_bias, const unsigned short* __restrict__ mperm,
    const float* __restrict__ scal, float* __restrict__ attn_out) {
  __shared__ float rb2[2112];
  __shared__ __align__(16) _Float16 khs[64 * 64];
  __shared__ __align__(16) float p32[64 * 68];

  const int bid = blockIdx.x;
  const int wg = ((bid & 7) << 7) | (bid >> 3);
  const int bh = wg >> 5, qt = wg & 31;
  const int b = bh >> 4, h = bh & 15;
  const int q0 = qt * 64;
  const int tid = threadIdx.x;
  const int w = tid >> 6, l = tid & 63, lg = l >> 4, lr = l & 15;

  for (int t = tid; t < 2112; t += 256)
    rb2[t] = rel_bias[(q0 + t) * 16 + h] * LOG2E - SHIFT2;

  const size_t bh_off = (size_t)bh * 2048 * 64;
  const _Float16* qhb = qh + bh_off;
  const char* khb = (const char*)(kh + bh_off);
  const unsigned short* mpb =
      mperm + (((size_t)(b * 32 + qt) * 32) * 256 + tid) * 16;
  float* attn_bh = attn_out + (size_t)bh * 2048 * 2048;

  f16x8 qf[2];
  {
    const size_t qrow = (size_t)(q0 + w * 16 + lr) * 64;
    qf[0] = ldh8(qhb + qrow + lg * 8);
    qf[1] = ldh8(qhb + qrow + 32 + lg * 8);
  }

  const int qbase = w * 16 + lg * 4;
  const float c1 = 0.125f * LOG2E;
  float4 inv4 = *reinterpret_cast<const float4*>(scal + (size_t)bh * 2048 + q0 + qbase);
  const float invs[4] = {inv4.x, inv4.y, inv4.z, inv4.w};

  // store geometry: thread covers row w*16+(l>>2), cols (l&3)*16 .. +15
  const int srow = w * 16 + (l >> 2);
  const int scb = (l & 3) * 16;
  const int e0 = w * 2 * 64 + l;

  for (int kt = 0; kt < 32; ++kt) {
    __syncthreads();
#pragma unroll
    for (int cc = 0; cc < 2; ++cc) {
      const int e = e0 + cc * 64;
      const int row = e >> 3, colb = (e & 7) << 4;
      const int srcb = (row << 7) + (colb ^ ((row & 7) << 4));
      gload_lds16(khb + (size_t)kt * 8192 + srcb, (char*)khs + e * 16);
    }
    u16x8 m0v = ldu8(mpb + (size_t)kt * 256 * 16);
    u16x8 m1v = ldu8(mpb + (size_t)kt * 256 * 16 + 8);
    __syncthreads();

#pragma unroll
    for (int c = 0; c < 4; ++c) {
      const int rowk = c * 16 + lr;
      f32x4 acc = {};
#pragma unroll
      for (int kk = 0; kk < 2; ++kk) {
        const int off = (rowk << 7) + (((kk << 6) + (lg << 4)) ^ ((rowk & 7) << 4));
        acc = MFMA16H(qf[kk], ldh8((const _Float16*)((const char*)khs + off)), acc);
      }
      const int kc = kt * 64 + c * 16 + lr;
#pragma unroll
      for (int r = 0; r < 4; ++r) {
        const float mbf = bf2f((c < 2) ? (unsigned short)m0v[(c & 1) * 4 + r]
                                       : (unsigned short)m1v[(c & 1) * 4 + r]);
        const float l2 = fmaf(acc[r], c1, rb2[qbase + r - kc + 2047]) + mbf;
        p32[(qbase + r) * 68 + c * 16 + lr] = EXP2F(l2) * invs[r];
      }
    }

    // wave-local vectorized store (rows 16w..16w+15 written by this wave)
    float* arow = attn_bh + (size_t)(q0 + srow) * 2048 + kt * 64 + scb;
#pragma unroll
    for (int i = 0; i < 4; ++i)
      *reinterpret_cast<float4*>(arow + i * 4) =
          *reinterpret_cast<const float4*>(&p32[srow * 68 + scb + i * 4]);
  }
}

// ---------------- host ----------------
extern "C" void kernel_launch(void* const* d_in, const int* in_sizes, int n_in,
                              void* d_out, int out_size, void* d_ws, size_t ws_size,
                              hipStream_t stream) {
  const float* q = (const float*)d_in[0];
  const float* k = (const float*)d_in[1];
  const float* v = (const float*)d_in[2];
  const float* mask = (const float*)d_in[3];
  const float* wq_w = (const float*)d_in[4];
  const float* wq_b = (const float*)d_in[5];
  const float* wk_w = (const float*)d_in[6];
  const float* wk_b = (const float*)d_in[7];
  const float* wv_w = (const float*)d_in[8];
  const float* wv_b = (const float*)d_in[9];
  const float* dw = (const float*)d_in[10];
  const float* db = (const float*)d_in[11];
  const float* rel = (const float*)d_in[12];

  char* ws = (char*)d_ws;
  _Float16* qf   = (_Float16*)(ws + 0);
  _Float16* kf   = (_Float16*)(ws + 8388608);
  _Float16* vf   = (_Float16*)(ws + 16777216);
  _Float16* wqf  = (_Float16*)(ws + 25165824);
  _Float16* wkf  = (_Float16*)(ws + 27262976);
  _Float16* wvf  = (_Float16*)(ws + 29360128);
  _Float16* dwf  = (_Float16*)(ws + 31457280);
  _Float16* qhf  = (_Float16*)(ws + 33554432);
  _Float16* khf  = (_Float16*)(ws + 41943040);
  _Float16* vhT  = (_Float16*)(ws + 50331648);
  _Float16* o_h  = (_Float16*)(ws + 58720256);
  float* scal    = (float*)(ws + 67108864);
  unsigned short* mperm = (unsigned short*)(ws + 67371008);

  float* out = (float*)d_out;
  float* attn_out = out + 4194304;

  prep_f16<<<4096, 256, 0, stream>>>(q, qf, 1048576);
  prep_f16<<<4096, 256, 0, stream>>>(k, kf, 1048576);
  prep_f16<<<4096, 256, 0, stream>>>(v, vf, 1048576);
  prep_f16<<<1024, 256, 0, stream>>>(wq_w, wqf, 262144);
  prep_f16<<<1024, 256, 0, stream>>>(wk_w, wkf, 262144);
  prep_f16<<<1024, 256, 0, stream>>>(wv_w, wvf, 262144);
  prep_f16<<<1024, 256, 0, stream>>>(dw, dwf, 262144);
  prep_mask_perm<<<2048, 256, 0, stream>>>(mask, mperm);

  gemm_kernel<0><<<256, 256, 0, stream>>>(qf, wqf, wq_b, qhf, nullptr);
  gemm_kernel<0><<<256, 256, 0, stream>>>(kf, wkf, wk_b, khf, nullptr);
  gemm_kernel<1><<<256, 256, 0, stream>>>(vf, wvf, wv_b, vhT, nullptr);

  attn_pv_kernel<<<1024, 256, 0, stream>>>(qhf, khf, vhT, rel, mperm, o_h, scal);
  attn_write_kernel<<<1024, 256, 0, stream>>>(qhf, khf, rel, mperm, scal, attn_out);

  gemm_kernel<2><<<256, 256, 0, stream>>>(o_h, dwf, db, nullptr, out);
}

// Round 5
// 606.658 us; speedup vs baseline: 2.3907x; 1.0730x over previous
//
#include <hip/hip_runtime.h>

typedef _Float16 f16x8 __attribute__((ext_vector_type(8)));
typedef _Float16 f16x4 __attribute__((ext_vector_type(4)));
typedef float f32x4 __attribute__((ext_vector_type(4)));
typedef unsigned short u16x8 __attribute__((ext_vector_type(8)));
typedef unsigned int u32;

#define MFMA16H(a, b, c) __builtin_amdgcn_mfma_f32_16x16x32_f16(a, b, c, 0, 0, 0)

#if __has_builtin(__builtin_amdgcn_exp2f)
#define EXP2F(x) __builtin_amdgcn_exp2f(x)
#else
#define EXP2F(x) exp2f(x)
#endif

#define LOG2E 1.44269504088896340736f
#define SHIFT2 14.0f   // log2-domain shift so unnormalized p fits fp16 comfortably

__device__ __forceinline__ unsigned short f2bf(float x) {
  unsigned u = __float_as_uint(x);
  u += 0x7FFF + ((u >> 16) & 1);   // round-to-nearest-even
  return (unsigned short)(u >> 16);
}
__device__ __forceinline__ float bf2f(unsigned short h) {
  return __uint_as_float(((unsigned)h) << 16);
}
__device__ __forceinline__ f16x8 ldh8(const _Float16* p) {
  return *reinterpret_cast<const f16x8*>(p);
}
__device__ __forceinline__ u16x8 ldu8(const unsigned short* p) {
  return *reinterpret_cast<const u16x8*>(p);
}
__device__ __forceinline__ f16x8 cvt8(float4 a, float4 b) {
  f16x8 r;
  r[0] = (_Float16)a.x; r[1] = (_Float16)a.y; r[2] = (_Float16)a.z; r[3] = (_Float16)a.w;
  r[4] = (_Float16)b.x; r[5] = (_Float16)b.y; r[6] = (_Float16)b.z; r[7] = (_Float16)b.w;
  return r;
}

// ---------------- mask -> permuted bf16( mask * -1e9 * log2e ) ----------------
// Layout: [(b*32+qt)*32+kt][lane 0..255][idx 0..15] u16, idx = c*4+r so an attn
// lane fetches its 16 fragment-ordered mask values as two dwordx4 loads.
__global__ __launch_bounds__(256) void prep_mask_perm(const float* __restrict__ src,
                                                      unsigned short* __restrict__ dst) {
  const int blk = blockIdx.x;               // (b*32+qt)*32 + kt
  const int kt = blk & 31, bq = blk >> 5;
  const int b = bq >> 5, qt = bq & 31;
  const int lane = threadIdx.x;
  const int w = lane >> 6, lg = (lane >> 4) & 3, lr = lane & 15;
  const int q0 = qt * 64;
  const float cs = -1e9f * LOG2E;
  unsigned short vals[16];
#pragma unroll
  for (int c = 0; c < 4; ++c)
#pragma unroll
    for (int r = 0; r < 4; ++r) {
      const int qr = q0 + w * 16 + lg * 4 + r;
      const int kc = kt * 64 + c * 16 + lr;
      vals[c * 4 + r] = f2bf(src[((size_t)b * 2048 + qr) * 2048 + kc] * cs);
    }
  uint4* out = reinterpret_cast<uint4*>(dst) + ((size_t)blk * 256 + lane) * 2;
  out[0] = *reinterpret_cast<uint4*>(&vals[0]);
  out[1] = *reinterpret_cast<uint4*>(&vals[8]);
}

// ---------------- fused projection GEMM (Q,K,V), fp32 inputs, fp16 out ----------------
// grid 768: mode = bid>>8 (0=Q head-split, 1=K head-split, 2=V transposed per head)
__global__ __launch_bounds__(256, 3) void proj_gemm_kernel(
    const float* __restrict__ qin, const float* __restrict__ kin, const float* __restrict__ vin,
    const float* __restrict__ wq, const float* __restrict__ wk, const float* __restrict__ wv,
    const float* __restrict__ bq, const float* __restrict__ bk, const float* __restrict__ bv,
    _Float16* __restrict__ qhf, _Float16* __restrict__ khf, _Float16* __restrict__ vhT) {
  __shared__ __align__(16) _Float16 As[128 * 32];
  __shared__ __align__(16) _Float16 Bs[128 * 32];

  const int mode = blockIdx.x >> 8;
  const int t = blockIdx.x & 255;
  const float* A = mode == 0 ? qin : (mode == 1 ? kin : vin);
  const float* B = mode == 0 ? wq : (mode == 1 ? wk : wv);
  const float* bias = mode == 0 ? bq : (mode == 1 ? bk : bv);
  _Float16* outp = mode == 0 ? qhf : (mode == 1 ? khf : vhT);

  const int tid = threadIdx.x;
  const int tm = t & 31, tn = t >> 5;
  const int m0 = tm * 128, n0 = tn * 128;
  const int w = tid >> 6, l = tid & 63, lg = l >> 4, lr = l & 15;
  const int wr = w >> 1, wc = w & 1;
  const int srow = tid >> 2, scol = (tid & 3) * 8;

  f32x4 acc[4][4] = {};

  for (int kt = 0; kt < 32; ++kt) {
    const int k0 = kt * 32;
    float4 ra[2][2], rb[2][2];
#pragma unroll
    for (int it = 0; it < 2; ++it) {
      const int row = it * 64 + srow;
      const float* pa = A + (size_t)(m0 + row) * 1024 + k0 + scol;
      const float* pb = B + (size_t)(n0 + row) * 1024 + k0 + scol;
      ra[it][0] = *reinterpret_cast<const float4*>(pa);
      ra[it][1] = *reinterpret_cast<const float4*>(pa + 4);
      rb[it][0] = *reinterpret_cast<const float4*>(pb);
      rb[it][1] = *reinterpret_cast<const float4*>(pb + 4);
    }
    __syncthreads();   // previous tile's frag reads complete
#pragma unroll
    for (int it = 0; it < 2; ++it) {
      const int eo = (it * 256 + tid) * 8;
      *reinterpret_cast<f16x8*>(As + eo) = cvt8(ra[it][0], ra[it][1]);
      *reinterpret_cast<f16x8*>(Bs + eo) = cvt8(rb[it][0], rb[it][1]);
    }
    __syncthreads();

    f16x8 fa[4], fb[4];
#pragma unroll
    for (int i = 0; i < 4; ++i) {
      fa[i] = ldh8(As + (wr * 64 + i * 16 + lr) * 32 + lg * 8);
      fb[i] = ldh8(Bs + (wc * 64 + i * 16 + lr) * 32 + lg * 8);
    }
#pragma unroll
    for (int i = 0; i < 4; ++i)
#pragma unroll
      for (int j = 0; j < 4; ++j)
        acc[i][j] = MFMA16H(fa[i], fb[j], acc[i][j]);
  }

#pragma unroll
  for (int i = 0; i < 4; ++i) {
    const int mrow = m0 + wr * 64 + i * 16 + lg * 4;
#pragma unroll
    for (int j = 0; j < 4; ++j) {
      const int ncol = n0 + wc * 64 + j * 16 + lr;
      const float bv = bias[ncol];
#pragma unroll
      for (int r = 0; r < 4; ++r) {
        const int m = mrow + r;
        const float v = acc[i][j][r] + bv;
        const int bb = m >> 11, s = m & 2047, hh = ncol >> 6, d = ncol & 63;
        if (mode != 2)
          outp[((size_t)(bb * 16 + hh) * 2048 + s) * 64 + d] = (_Float16)v;
        else
          outp[((size_t)(bb * 16 + hh) * 64 + d) * 2048 + s] = (_Float16)v;
      }
    }
  }
}

// ---------------- dense GEMM: fp16 A (o_h), fp32 B (dense_w), fp32 out ----------------
__global__ __launch_bounds__(256) void dense_gemm_kernel(
    const _Float16* __restrict__ A, const float* __restrict__ B,
    const float* __restrict__ bias, float* __restrict__ out_f) {
  __shared__ __align__(16) _Float16 As[128 * 32];
  __shared__ __align__(16) _Float16 Bs[128 * 32];

  const int tid = threadIdx.x;
  const int tm = blockIdx.x & 31, tn = blockIdx.x >> 5;
  const int m0 = tm * 128, n0 = tn * 128;
  const int w = tid >> 6, l = tid & 63, lg = l >> 4, lr = l & 15;
  const int wr = w >> 1, wc = w & 1;
  const int srow = tid >> 2, scol = (tid & 3) * 8;

  f32x4 acc[4][4] = {};

  for (int kt = 0; kt < 32; ++kt) {
    const int k0 = kt * 32;
    uint4 ra[2];
    float4 rb[2][2];
#pragma unroll
    for (int it = 0; it < 2; ++it) {
      const int row = it * 64 + srow;
      ra[it] = *reinterpret_cast<const uint4*>(A + (size_t)(m0 + row) * 1024 + k0 + scol);
      const float* pb = B + (size_t)(n0 + row) * 1024 + k0 + scol;
      rb[it][0] = *reinterpret_cast<const float4*>(pb);
      rb[it][1] = *reinterpret_cast<const float4*>(pb + 4);
    }
    __syncthreads();
#pragma unroll
    for (int it = 0; it < 2; ++it) {
      const int eo = (it * 256 + tid) * 8;
      *reinterpret_cast<uint4*>(As + eo) = ra[it];
      *reinterpret_cast<f16x8*>(Bs + eo) = cvt8(rb[it][0], rb[it][1]);
    }
    __syncthreads();

    f16x8 fa[4], fb[4];
#pragma unroll
    for (int i = 0; i < 4; ++i) {
      fa[i] = ldh8(As + (wr * 64 + i * 16 + lr) * 32 + lg * 8);
      fb[i] = ldh8(Bs + (wc * 64 + i * 16 + lr) * 32 + lg * 8);
    }
#pragma unroll
    for (int i = 0; i < 4; ++i)
#pragma unroll
      for (int j = 0; j < 4; ++j)
        acc[i][j] = MFMA16H(fa[i], fb[j], acc[i][j]);
  }

#pragma unroll
  for (int i = 0; i < 4; ++i) {
    const int mrow = m0 + wr * 64 + i * 16 + lg * 4;
#pragma unroll
    for (int j = 0; j < 4; ++j) {
      const int ncol = n0 + wc * 64 + j * 16 + lr;
      const float bv = bias[ncol];
#pragma unroll
      for (int r = 0; r < 4; ++r)
        out_f[(size_t)(mrow + r) * 1024 + ncol] = acc[i][j][r] + bv;
    }
  }
}

// ---------------- attention pass 1: QK^T + exp + row sums + PV ----------------
// Barrier-free kt loop: K and V read directly from global (L2-resident per
// XCD thanks to the swizzle); p routed through wave-local LDS only.
__global__ __launch_bounds__(256, 3) void attn_pv_kernel(
    const _Float16* __restrict__ qh, const _Float16* __restrict__ kh,
    const _Float16* __restrict__ vT,
    const float* __restrict__ rel_bias, const unsigned short* __restrict__ mperm,
    _Float16* __restrict__ o_h, float* __restrict__ scal) {
  __shared__ float rb2[2112];
  __shared__ __align__(16) _Float16 p_lds[64 * 76];

  const int bid = blockIdx.x;
  const int wg = ((bid & 7) << 7) | (bid >> 3);   // XCD-chunked: 4 bh per XCD
  const int bh = wg >> 5, qt = wg & 31;
  const int b = bh >> 4, h = bh & 15;
  const int q0 = qt * 64;
  const int tid = threadIdx.x;
  const int w = tid >> 6, l = tid & 63, lg = l >> 4, lr = l & 15;

  for (int t = tid; t < 2111; t += 256)
    rb2[t] = rel_bias[(q0 + t) * 16 + h] * LOG2E - SHIFT2;

  const size_t bh_off = (size_t)bh * 2048 * 64;
  const _Float16* qhb = qh + bh_off;
  const _Float16* khb = kh + bh_off;
  const _Float16* vTb = vT + bh_off;
  const unsigned short* mpb =
      mperm + (((size_t)(b * 32 + qt) * 32) * 256 + tid) * 16;

  f16x8 qf[2];
  {
    const size_t qrow = (size_t)(q0 + w * 16 + lr) * 64;
    qf[0] = ldh8(qhb + qrow + lg * 8);
    qf[1] = ldh8(qhb + qrow + 32 + lg * 8);
  }
  __syncthreads();  // rb2 ready (only barrier in the kernel)

  const int qbase = w * 16 + lg * 4;
  const float c1 = 0.125f * LOG2E;
  float sacc[4] = {0.f, 0.f, 0.f, 0.f};
  f32x4 acc_o[4] = {};

  for (int kt = 0; kt < 32; ++kt) {
    u16x8 m0v = ldu8(mpb + (size_t)kt * 4096);
    u16x8 m1v = ldu8(mpb + (size_t)kt * 4096 + 8);
#pragma unroll
    for (int c = 0; c < 4; ++c) {
      const int kc = kt * 64 + c * 16 + lr;
      const _Float16* kr = khb + (size_t)kc * 64 + lg * 8;
      f32x4 acc = {};
      acc = MFMA16H(qf[0], ldh8(kr), acc);
      acc = MFMA16H(qf[1], ldh8(kr + 32), acc);
#pragma unroll
      for (int r = 0; r < 4; ++r) {
        const float mbf = bf2f((c < 2) ? (unsigned short)m0v[(c & 1) * 4 + r]
                                       : (unsigned short)m1v[(c & 1) * 4 + r]);
        const float l2 = fmaf(acc[r], c1, rb2[qbase + r - kc + 2047]) + mbf;
        const float p = EXP2F(l2);
        sacc[r] += p;
        p_lds[(qbase + r) * 76 + c * 16 + lr] = (_Float16)p;
      }
    }
    // PV: p rows are wave-local (lgkmcnt ordering, no barrier)
    f16x8 pf0 = ldh8(p_lds + (w * 16 + lr) * 76 + lg * 8);
    f16x8 pf1 = ldh8(p_lds + (w * 16 + lr) * 76 + 32 + lg * 8);
#pragma unroll
    for (int n = 0; n < 4; ++n) {
      const _Float16* vr = vTb + (size_t)(n * 16 + lr) * 2048 + kt * 64 + lg * 8;
      acc_o[n] = MFMA16H(pf0, ldh8(vr), acc_o[n]);
      acc_o[n] = MFMA16H(pf1, ldh8(vr + 32), acc_o[n]);
    }
  }

  float inv_s[4];
#pragma unroll
  for (int r = 0; r < 4; ++r) {
    float s = sacc[r];
    s += __shfl_xor(s, 1);
    s += __shfl_xor(s, 2);
    s += __shfl_xor(s, 4);
    s += __shfl_xor(s, 8);
    inv_s[r] = 1.0f / s;
    if (lr == 0) scal[(size_t)bh * 2048 + q0 + qbase + r] = inv_s[r];
  }

#pragma unroll
  for (int n = 0; n < 4; ++n)
#pragma unroll
    for (int r = 0; r < 4; ++r) {
      const int qr = q0 + qbase + r;
      const int d = n * 16 + lr;
      o_h[((size_t)(b * 2048 + qr) * 16 + h) * 64 + d] = (_Float16)(acc_o[n][r] * inv_s[r]);
    }
}

// ---------------- attention pass 2: recompute QK^T, write normalized attn ----------------
__global__ __launch_bounds__(256, 4) void attn_write_kernel(
    const _Float16* __restrict__ qh, const _Float16* __restrict__ kh,
    const float* __restrict__ rel_bias, const unsigned short* __restrict__ mperm,
    const float* __restrict__ scal, float* __restrict__ attn_out) {
  __shared__ float rb2[2112];
  __shared__ __align__(16) float p32[64 * 68];

  const int bid = blockIdx.x;
  const int wg = ((bid & 7) << 7) | (bid >> 3);
  const int bh = wg >> 5, qt = wg & 31;
  const int b = bh >> 4, h = bh & 15;
  const int q0 = qt * 64;
  const int tid = threadIdx.x;
  const int w = tid >> 6, l = tid & 63, lg = l >> 4, lr = l & 15;

  for (int t = tid; t < 2111; t += 256)
    rb2[t] = rel_bias[(q0 + t) * 16 + h] * LOG2E - SHIFT2;

  const size_t bh_off = (size_t)bh * 2048 * 64;
  const _Float16* qhb = qh + bh_off;
  const _Float16* khb = kh + bh_off;
  const unsigned short* mpb =
      mperm + (((size_t)(b * 32 + qt) * 32) * 256 + tid) * 16;
  float* attn_bh = attn_out + (size_t)bh * 2048 * 2048;

  f16x8 qf[2];
  {
    const size_t qrow = (size_t)(q0 + w * 16 + lr) * 64;
    qf[0] = ldh8(qhb + qrow + lg * 8);
    qf[1] = ldh8(qhb + qrow + 32 + lg * 8);
  }
  __syncthreads();  // rb2 ready (only barrier in the kernel)

  const int qbase = w * 16 + lg * 4;
  const float c1 = 0.125f * LOG2E;
  float4 inv4 = *reinterpret_cast<const float4*>(scal + (size_t)bh * 2048 + q0 + qbase);
  const float invs[4] = {inv4.x, inv4.y, inv4.z, inv4.w};

  // store geometry: thread covers row w*16+(l>>2), cols (l&3)*16 .. +15
  const int srow = w * 16 + (l >> 2);
  const int scb = (l & 3) * 16;

  for (int kt = 0; kt < 32; ++kt) {
    u16x8 m0v = ldu8(mpb + (size_t)kt * 4096);
    u16x8 m1v = ldu8(mpb + (size_t)kt * 4096 + 8);
#pragma unroll
    for (int c = 0; c < 4; ++c) {
      const int kc = kt * 64 + c * 16 + lr;
      const _Float16* kr = khb + (size_t)kc * 64 + lg * 8;
      f32x4 acc = {};
      acc = MFMA16H(qf[0], ldh8(kr), acc);
      acc = MFMA16H(qf[1], ldh8(kr + 32), acc);
#pragma unroll
      for (int r = 0; r < 4; ++r) {
        const float mbf = bf2f((c < 2) ? (unsigned short)m0v[(c & 1) * 4 + r]
                                       : (unsigned short)m1v[(c & 1) * 4 + r]);
        const float l2 = fmaf(acc[r], c1, rb2[qbase + r - kc + 2047]) + mbf;
        p32[(qbase + r) * 68 + c * 16 + lr] = EXP2F(l2) * invs[r];
      }
    }
    // wave-local vectorized store (rows 16w..16w+15 written by this wave)
    float* arow = attn_bh + (size_t)(q0 + srow) * 2048 + kt * 64 + scb;
#pragma unroll
    for (int i = 0; i < 4; ++i)
      *reinterpret_cast<float4*>(arow + i * 4) =
          *reinterpret_cast<const float4*>(&p32[srow * 68 + scb + i * 4]);
  }
}

// ---------------- host ----------------
extern "C" void kernel_launch(void* const* d_in, const int* in_sizes, int n_in,
                              void* d_out, int out_size, void* d_ws, size_t ws_size,
                              hipStream_t stream) {
  const float* q = (const float*)d_in[0];
  const float* k = (const float*)d_in[1];
  const float* v = (const float*)d_in[2];
  const float* mask = (const float*)d_in[3];
  const float* wq_w = (const float*)d_in[4];
  const float* wq_b = (const float*)d_in[5];
  const float* wk_w = (const float*)d_in[6];
  const float* wk_b = (const float*)d_in[7];
  const float* wv_w = (const float*)d_in[8];
  const float* wv_b = (const float*)d_in[9];
  const float* dw = (const float*)d_in[10];
  const float* db = (const float*)d_in[11];
  const float* rel = (const float*)d_in[12];

  char* ws = (char*)d_ws;
  _Float16* qhf  = (_Float16*)(ws + 0);
  _Float16* khf  = (_Float16*)(ws + 8388608);
  _Float16* vhT  = (_Float16*)(ws + 16777216);
  _Float16* o_h  = (_Float16*)(ws + 25165824);
  float* scal    = (float*)(ws + 33554432);
  unsigned short* mperm = (unsigned short*)(ws + 33816576);

  float* out = (float*)d_out;
  float* attn_out = out + 4194304;

  prep_mask_perm<<<2048, 256, 0, stream>>>(mask, mperm);

  proj_gemm_kernel<<<768, 256, 0, stream>>>(q, k, v, wq_w, wk_w, wv_w,
                                            wq_b, wk_b, wv_b, qhf, khf, vhT);

  attn_pv_kernel<<<1024, 256, 0, stream>>>(qhf, khf, vhT, rel, mperm, o_h, scal);
  attn_write_kernel<<<1024, 256, 0, stream>>>(qhf, khf, rel, mperm, scal, attn_out);

  dense_gemm_kernel<<<256, 256, 0, stream>>>(o_h, dw, db, out);
}